// Round 16
// baseline (281.731 us; speedup 1.0000x reference)
//
#include <hip/hip_runtime.h>
#include <stdint.h>

// DecoderLayer: B=2, S=2048, DIM=1024, H=16, DH=64, DFF=2048
// Round 16: R15 base + in-register P redistribution via __shfl (no lP LDS
// buffer, no P bank conflicts) in BOTH attn kernels. Derivation: swapped-QK
// leaves lane (g,q) with P[q][16nf+4g+r]; PV A-frag for k-slot m=4kk+g needs
// w[2kk+(g>>1)][j&1] from lanes 32(g&1)+q and +16 -> 8 shfl + 4 sel per kk.
// attn2 LDS 48K->32K (3->5 blocks/CU). Everything else = R15 (best, 264.8us).

#define DEV static __device__ __forceinline__

typedef __attribute__((ext_vector_type(8))) __bf16 bf16x8;           // MFMA A/B
typedef __attribute__((ext_vector_type(8))) unsigned short u16x8;
typedef __attribute__((ext_vector_type(4))) uint32_t u32x4;
typedef __attribute__((ext_vector_type(4))) float f32x4;

DEV float bf2f(uint16_t u) { union { uint32_t u; float f; } v; v.u = ((uint32_t)u) << 16; return v.f; }
DEV uint16_t f2bf(float f) {
  union { float f; uint32_t u; } v; v.f = f;
  uint32_t r = v.u + 0x7fffu + ((v.u >> 16) & 1u);
  return (uint16_t)(r >> 16);
}
DEV uint16_t f2bf_hw(float f) { return __builtin_bit_cast(unsigned short, (__bf16)f); }
DEV uint32_t pack2(float a, float b) { return ((uint32_t)f2bf_hw(b) << 16) | f2bf_hw(a); }

DEV bf16x8 asbf(u16x8 v) { return __builtin_bit_cast(bf16x8, v); }
DEV f32x4 mfma32(bf16x8 a, bf16x8 b, f32x4 c) {
  return __builtin_amdgcn_mfma_f32_16x16x32_bf16(a, b, c, 0, 0, 0);
}

// async global->LDS, 16B per lane (attn staging).
DEV void gload_lds16(const void* g, void* l) {
  __builtin_amdgcn_global_load_lds(
      (const __attribute__((address_space(1))) uint32_t*)g,
      (__attribute__((address_space(3))) uint32_t*)l, 16, 0, 0);
}

// XOR swizzle: 16B slot s of row r <-> slot s^(r&7). Rows are 64 bf16 = 128B.
DEV int swz(int row, int slot) { return slot ^ (row & 7); }

DEV bf16x8 frag8(const uint16_t* l, int row, int slot) {
  u16x8 v = *(const u16x8*)((const char*)l + row * 128 + (swz(row, slot) << 4));
  return asbf(v);
}

// attn1 block decode tables: 63 blocks per (h,b); qt desc (longest chains first)
__constant__ uint8_t QT_TAB[63] = {
  31,31,31,30,30,30,29,29,29,28,28,28,27,27,27,26,26,26,25,25,25,24,24,24,
  23,23,23,22,22,22,
  21,21,20,20,19,19,18,18,17,17,16,16,15,15,14,14,13,13,12,12,11,11,
  10,9,8,7,6,5,4,3,2,1,0};
__constant__ uint8_t SP_TAB[63] = {
  0,1,2,0,1,2,0,1,2,0,1,2,0,1,2,0,1,2,0,1,2,0,1,2,
  0,1,2,0,1,2,
  0,1,0,1,0,1,0,1,0,1,0,1,0,1,0,1,0,1,0,1,0,1,
  0,0,0,0,0,0,0,0,0,0,0};

// ---------------- dtype probe ----------------
__global__ void probe_k(const uint32_t* __restrict__ mask, uint32_t* __restrict__ flag) {
  flag[0] = (mask[1] & 0xFFFFu) ? 1u : 0u;   // 1 = bf16, 0 = f32
}

// ---------------- ingest convert (f32 path only; no-op when bf16) ----------------
__global__ __launch_bounds__(256) void cvt_k(const void* __restrict__ src,
                                             uint16_t* __restrict__ dst, int n,
                                             const uint32_t* __restrict__ flag) {
  if (flag[0]) return;
  const int stride = gridDim.x * 256 * 8;
  for (int i = (blockIdx.x * 256 + threadIdx.x) * 8; i < n; i += stride) {
    const float* sf = (const float*)src + i;
    u16x8 o;
    for (int j = 0; j < 8; j++) o[j] = f2bf(sf[j]);
    *(u16x8*)(dst + i) = o;
  }
}

// ---------------- generic transpose+convert+scale: in[b][R][C] -> out[b][C][R] ----------------
__global__ __launch_bounds__(256) void transpose_k(const void* __restrict__ in_,
                                                   uint16_t* __restrict__ out, int R, int C,
                                                   float scale,
                                                   const uint32_t* __restrict__ flag) {
  __shared__ uint16_t t[32][33];
  const int isbf = (int)flag[0];
  const int b = blockIdx.z;
  const float* in_f = (const float*)in_ + (size_t)b * R * C;
  const uint16_t* in_u = (const uint16_t*)in_ + (size_t)b * R * C;
  out += (size_t)b * R * C;
  const int c0 = blockIdx.x * 32, r0 = blockIdx.y * 32;
  const int tx = threadIdx.x & 31, ty = threadIdx.x >> 5;
  for (int i = 0; i < 4; i++) {
    int r = ty + i * 8;
    size_t idx = (size_t)(r0 + r) * C + c0 + tx;
    uint16_t v;
    if (isbf) v = (scale == 1.0f) ? in_u[idx] : f2bf(bf2f(in_u[idx]) * scale);
    else      v = f2bf(in_f[idx] * scale);
    t[r][tx] = v;
  }
  __syncthreads();
  for (int i = 0; i < 4; i++) {
    int r = ty + i * 8;
    out[(size_t)(c0 + r) * R + r0 + tx] = t[tx][r];
  }
}

// ---------------- fused QKV weight transpose: Wq/Wk/Wv [16][1024][64] -> Wt[3072][1024] ----------------
__global__ __launch_bounds__(256) void transpose_qkv_k(const void* __restrict__ Wq,
                                                       const void* __restrict__ Wk,
                                                       const void* __restrict__ Wv,
                                                       uint16_t* __restrict__ out,
                                                       const uint32_t* __restrict__ flag) {
  __shared__ uint16_t t[32][33];
  const int isbf = (int)flag[0];
  const int which = blockIdx.z >> 4, hh = blockIdx.z & 15;
  const void* in_ = (which == 0 ? Wq : which == 1 ? Wk : Wv);
  const float scale = (which == 0) ? 0.180336880f : 1.0f;   // 0.125*log2(e)
  const int R = 1024, C = 64;
  const float* in_f = (const float*)in_ + (size_t)hh * R * C;
  const uint16_t* in_u = (const uint16_t*)in_ + (size_t)hh * R * C;
  out += ((size_t)which * 16 + hh) * R * C;
  const int c0 = blockIdx.x * 32, r0 = blockIdx.y * 32;
  const int tx = threadIdx.x & 31, ty = threadIdx.x >> 5;
  for (int i = 0; i < 4; i++) {
    int r = ty + i * 8;
    size_t idx = (size_t)(r0 + r) * C + c0 + tx;
    uint16_t v;
    if (isbf) v = (scale == 1.0f) ? in_u[idx] : f2bf(bf2f(in_u[idx]) * scale);
    else      v = f2bf(in_f[idx] * scale);
    t[r][tx] = v;
  }
  __syncthreads();
  for (int i = 0; i < 4; i++) {
    int r = ty + i * 8;
    out[(size_t)(c0 + r) * R + r0 + tx] = t[tx][r];
  }
}

// ---------------- fused QKV projection: C[4096][3072] = A @ Wt^T (R8 structure) ----------------
__global__ __launch_bounds__(256) void proj_k(
    const uint16_t* __restrict__ Aqk_c, const void* __restrict__ Aqk_r,
    const uint16_t* __restrict__ Av_c, const void* __restrict__ Av_r,
    const uint16_t* __restrict__ Wt,
    uint16_t* __restrict__ Q, uint16_t* __restrict__ K, uint16_t* __restrict__ Vt,
    const uint32_t* __restrict__ flag) {
  __shared__ __attribute__((aligned(16))) uint16_t lA[2][128 * 64];
  __shared__ __attribute__((aligned(16))) uint16_t lB[2][128 * 64];
  const int isbf = (int)flag[0];
  const uint16_t* Aqk = isbf ? (const uint16_t*)Aqk_r : Aqk_c;
  const uint16_t* Av  = isbf ? (const uint16_t*)Av_r  : Av_c;
  const int tid = threadIdx.x, lane = tid & 63, wave = tid >> 6;
  const int g = lane >> 4;
  const int m0 = blockIdx.x * 128, n0 = blockIdx.y * 128;
  const int proj = n0 >> 10;
  const uint16_t* A = (proj == 2 ? Av : Aqk);
  const uint16_t* Bt = Wt + (size_t)n0 * 1024;
  const int wm = wave >> 1, wn = wave & 1;
  f32x4 acc[4][4] = {};
  u16x8 ra[4], rb[4];
  const int row0 = tid >> 3, slot0 = tid & 7;
  auto loadT = [&](int kt) {
    for (int i = 0; i < 4; i++) {
      int row = row0 + i * 32;
      ra[i] = *(const u16x8*)(A + (size_t)(m0 + row) * 1024 + kt + slot0 * 8);
      rb[i] = *(const u16x8*)(Bt + (size_t)row * 1024 + kt + slot0 * 8);
    }
  };
  auto writeT = [&](int buf) {
    for (int i = 0; i < 4; i++) {
      int row = row0 + i * 32;
      *(u16x8*)&lA[buf][(row * 8 + swz(row, slot0)) * 8] = ra[i];
      *(u16x8*)&lB[buf][(row * 8 + swz(row, slot0)) * 8] = rb[i];
    }
  };
  loadT(0);
  writeT(0);
  int cur = 0;
  for (int it = 0; it < 16; it++) {
    const int more = (it < 15);
    if (more) loadT((it + 1) * 64);
    __syncthreads();
    for (int kk = 0; kk < 2; kk++) {
      bf16x8 af[4], bfr[4];
      for (int fm = 0; fm < 4; fm++) af[fm] = frag8(lA[cur], wm * 64 + fm * 16 + (lane & 15), kk * 4 + g);
      for (int fn = 0; fn < 4; fn++) bfr[fn] = frag8(lB[cur], wn * 64 + fn * 16 + (lane & 15), kk * 4 + g);
      for (int fm = 0; fm < 4; fm++)
        for (int fn = 0; fn < 4; fn++)
          acc[fm][fn] = mfma32(af[fm], bfr[fn], acc[fm][fn]);
    }
    if (more) writeT(cur ^ 1);
    cur ^= 1;
  }
  if (proj != 2) {
    uint16_t* outp = (proj == 0 ? Q : K);
    for (int fm = 0; fm < 4; fm++)
      for (int fn = 0; fn < 4; fn++)
        for (int r = 0; r < 4; r++) {
          int row = m0 + wm * 64 + fm * 16 + g * 4 + r;
          int b = row >> 11, s = row & 2047;
          int col = n0 + wn * 64 + fn * 16 + (lane & 15);
          int h = (col >> 6) & 15, e = col & 63;
          outp[(((size_t)(b * 16 + h)) * 2048 + s) * 64 + e] = f2bf(acc[fm][fn][r]);
        }
  } else {
    __syncthreads();
    uint16_t* tv = (uint16_t*)lA;   // 32 KB: 128 cols x 256B
    for (int fm = 0; fm < 4; fm++)
      for (int fn = 0; fn < 4; fn++)
        for (int r = 0; r < 4; r++) {
          int rl = wm * 64 + fm * 16 + g * 4 + r;
          int cl = wn * 64 + fn * 16 + (lane & 15);
          int byte = rl * 2;
          *(uint16_t*)((char*)tv + cl * 256 + ((((byte >> 4)) ^ (cl & 15)) << 4) + (byte & 15)) =
              f2bf(acc[fm][fn][r]);
        }
    __syncthreads();
    const int b = m0 >> 11, s0 = m0 & 2047;
    const int c = tid >> 1, half = tid & 1;
    const int col = n0 + c;
    const int h = (col >> 6) & 15, e = col & 63;
    uint16_t* dst = Vt + (((size_t)(b * 16 + h)) * 64 + e) * 2048 + s0 + half * 64;
    for (int j = 0; j < 8; j++) {
      int rl = half * 64 + j * 8;
      u16x8 v = *(const u16x8*)((const char*)tv + c * 256 + (((rl >> 3) ^ (c & 15)) << 4));
      *(u16x8*)(dst + j * 8) = v;
    }
  }
}

// ---------------- causal flash attention: single-group, CHUNK=11, shfl-P ----------------
// grid (63, 16, 2). (qt, split) from QT_TAB/SP_TAB; tiles [11*split, min(+11, qt+1)).
__global__ __launch_bounds__(256) void attn1_k(const uint16_t* __restrict__ Q,
                                               const uint16_t* __restrict__ K,
                                               const uint16_t* __restrict__ Vt,
                                               uint16_t* __restrict__ Op0,
                                               uint16_t* __restrict__ Op1,
                                               uint16_t* __restrict__ Op2,
                                               float* __restrict__ lbuf) {
  __shared__ __attribute__((aligned(16))) uint16_t lK[2][64 * 64];
  __shared__ __attribute__((aligned(16))) uint16_t lV[2][64 * 64];
  const int tid = threadIdx.x, lane = tid & 63, wave = tid >> 6;
  const int g = lane >> 4, qrow = lane & 15;
  const int bx = blockIdx.x, h = blockIdx.y, b = blockIdx.z;
  const int qt = QT_TAB[bx], split = SP_TAB[bx];
  const int kt0 = split * 11;
  const int lim = qt + 1;
  const int kt1 = (kt0 + 11 < lim) ? kt0 + 11 : lim;
  const size_t bh = (size_t)(b * 16 + h);
  const uint16_t* Qg = Q + bh * 2048 * 64;
  const uint16_t* Kg = K + bh * 2048 * 64;
  const uint16_t* Vg = Vt + bh * 64 * 2048;
  bf16x8 ones;
  for (int j = 0; j < 8; j++) ones[j] = (__bf16)1.0f;
  const int lrow = lane >> 3, sl = lane & 7;
  auto STAGE = [&](int buf, int kt) {
    for (int i = 0; i < 2; i++) {
      int cb = (i * 4 + wave) * 64;
      int row = (cb >> 3) + lrow;
      int so = swz(row, sl) << 3;
      gload_lds16(Kg + (size_t)(kt * 64 + row) * 64 + so, &lK[buf][cb * 8]);
      gload_lds16(Vg + (size_t)row * 2048 + kt * 64 + so, &lV[buf][cb * 8]);
    }
  };
  const int q0 = qt * 64;
  bf16x8 qf[2];
  {
    int row = q0 + wave * 16 + qrow;
    for (int kk = 0; kk < 2; kk++)
      qf[kk] = asbf(*(const u16x8*)(Qg + (size_t)row * 64 + kk * 32 + g * 8));
  }
  f32x4 oacc[4] = {};
  f32x4 acc_l = {};
  const int pl0 = ((lane >> 4) & 1) * 32 + qrow;   // source lane 0
  const int pl1 = pl0 + 16;                        // source lane 1
  const bool phi = (lane >> 5) & 1;                // g>>1
  STAGE(0, kt0);
  int buf = 0;
  for (int kt = kt0; kt < kt1; kt++) {
    __syncthreads();
    if (kt + 1 < kt1) STAGE(buf ^ 1, kt + 1);
    f32x4 s[4] = {};
    for (int kk = 0; kk < 2; kk++)
      for (int nf = 0; nf < 4; nf++)
        s[nf] = mfma32(frag8(lK[buf], nf * 16 + qrow, kk * 4 + g), qf[kk], s[nf]);
    if (kt == qt) {
      for (int nf = 0; nf < 4; nf++)
        for (int r = 0; r < 4; r++) {
          int kloc = nf * 16 + g * 4 + r;
          if (kloc > wave * 16 + qrow) s[nf][r] = -1e9f;
        }
    }
    // p + pack into w8[nf*2 + word]
    uint32_t w8[8];
#pragma unroll
    for (int nf = 0; nf < 4; nf++) {
      float p0 = __builtin_amdgcn_exp2f(s[nf][0]);
      float p1 = __builtin_amdgcn_exp2f(s[nf][1]);
      float p2 = __builtin_amdgcn_exp2f(s[nf][2]);
      float p3 = __builtin_amdgcn_exp2f(s[nf][3]);
      w8[nf * 2] = pack2(p0, p1);
      w8[nf * 2 + 1] = pack2(p2, p3);
    }
    // PV with in-register P redistribution
#pragma unroll
    for (int kk = 0; kk < 2; kk++) {
      uint32_t a0 = (uint32_t)__shfl((int)w8[4 * kk + 0], pl0);
      uint32_t b0 = (uint32_t)__shfl((int)w8[4 * kk + 2], pl0);
      uint32_t a1 = (uint32_t)__shfl((int)w8[4 * kk + 1], pl0);
      uint32_t b1 = (uint32_t)__shfl((int)w8[4 * kk + 3], pl0);
      uint32_t a2 = (uint32_t)__shfl((int)w8[4 * kk + 0], pl1);
      uint32_t b2 = (uint32_t)__shfl((int)w8[4 * kk + 2], pl1);
      uint32_t a3 = (uint32_t)__shfl((int)w8[4 * kk + 1], pl1);
      uint32_t b3 = (uint32_t)__shfl((int)w8[4 * kk + 3], pl1);
      u32x4 pv4;
      pv4[0] = phi ? b0 : a0;
      pv4[1] = phi ? b1 : a1;
      pv4[2] = phi ? b2 : a2;
      pv4[3] = phi ? b3 : a3;
      bf16x8 pa = __builtin_bit_cast(bf16x8, pv4);
      acc_l = mfma32(pa, ones, acc_l);
      for (int df = 0; df < 4; df++)
        oacc[df] = mfma32(pa, frag8(lV[buf], df * 16 + qrow, kk * 4 + g), oacc[df]);
    }
    buf ^= 1;
  }
  uint16_t* Op = (split == 0) ? Op0 : (split == 1) ? Op1 : Op2;
  for (int df = 0; df < 4; df++)
    for (int r = 0; r < 4; r++) {
      int srow = q0 + wave * 16 + g * 4 + r;
      int e = df * 16 + qrow;
      Op[((size_t)b * 2048 + srow) * 1024 + h * 64 + e] = f2bf(oacc[df][r]);
    }
  if (qrow == 0) {
    for (int r = 0; r < 4; r++) {
      int srow = q0 + wave * 16 + g * 4 + r;
      lbuf[((size_t)(split * 2 + b) * 16 + h) * 2048 + srow] = acc_l[r];
    }
  }
}

// ---------------- merge (attn1): conditional 1/2/3-way by qt ----------------
__global__ __launch_bounds__(256) void merge3_k(const uint16_t* __restrict__ O0,
                                                const uint16_t* __restrict__ O1,
                                                const uint16_t* __restrict__ O2,
                                                const float* __restrict__ lbuf,
                                                uint16_t* __restrict__ out) {
  int i = (blockIdx.x * 256 + threadIdx.x) * 8;
  int sg = i >> 10;
  int b = sg >> 11, s = sg & 2047;
  int h = (i & 1023) >> 6;
  const int qt = s >> 6;
  const int nch = (qt + 11) / 11;               // ceil((qt+1)/11)
  float l = lbuf[((size_t)b * 16 + h) * 2048 + s];
  u16x8 o0 = *(const u16x8*)(O0 + i);
  float acc[8];
  for (int j = 0; j < 8; j++) acc[j] = bf2f(o0[j]);
  if (nch >= 2) {
    l += lbuf[((size_t)(2 + b) * 16 + h) * 2048 + s];
    u16x8 o1 = *(const u16x8*)(O1 + i);
    for (int j = 0; j < 8; j++) acc[j] += bf2f(o1[j]);
  }
  if (nch >= 3) {
    l += lbuf[((size_t)(4 + b) * 16 + h) * 2048 + s];
    u16x8 o2 = *(const u16x8*)(O2 + i);
    for (int j = 0; j < 8; j++) acc[j] += bf2f(o2[j]);
  }
  float inv = 1.f / l;
  u16x8 o;
  for (int j = 0; j < 8; j++) o[j] = f2bf(acc[j] * inv);
  *(u16x8*)(out + i) = o;
}

// ---------------- non-causal flash attention: dual-group, 4-way split, shfl-P ----------------
__global__ __launch_bounds__(256) void attn2_k(const uint16_t* __restrict__ Q,
                                               const uint16_t* __restrict__ K,
                                               const uint16_t* __restrict__ Vt,
                                               uint16_t* __restrict__ Op0,
                                               uint16_t* __restrict__ Op1,
                                               uint16_t* __restrict__ Op2,
                                               uint16_t* __restrict__ Op3,
                                               float* __restrict__ lbuf) {
  __shared__ __attribute__((aligned(16))) uint16_t lK[2][64 * 64];
  __shared__ __attribute__((aligned(16))) uint16_t lV[2][64 * 64];
  const int tid = threadIdx.x, lane = tid & 63, wave = tid >> 6;
  const int g = lane >> 4, qrow = lane & 15;
  const int bx = blockIdx.x, h = blockIdx.y, b = blockIdx.z;
  const int pair = bx >> 2, split = bx & 3;
  const int kt0 = split * 8, kt1 = kt0 + 8;
  const int q0 = pair * 128;
  const size_t bh = (size_t)(b * 16 + h);
  const uint16_t* Qg = Q + bh * 2048 * 64;
  const uint16_t* Kg = K + bh * 2048 * 64;
  const uint16_t* Vg = Vt + bh * 64 * 2048;
  bf16x8 ones;
  for (int j = 0; j < 8; j++) ones[j] = (__bf16)1.0f;
  const int lrow = lane >> 3, sl = lane & 7;
  auto STAGE = [&](int buf, int kt) {
    for (int i = 0; i < 2; i++) {
      int cb = (i * 4 + wave) * 64;
      int row = (cb >> 3) + lrow;
      int so = swz(row, sl) << 3;
      gload_lds16(Kg + (size_t)(kt * 64 + row) * 64 + so, &lK[buf][cb * 8]);
      gload_lds16(Vg + (size_t)row * 2048 + kt * 64 + so, &lV[buf][cb * 8]);
    }
  };
  bf16x8 qf[2][2];
#pragma unroll
  for (int grp = 0; grp < 2; grp++) {
    int row = q0 + grp * 64 + wave * 16 + qrow;
    for (int kk = 0; kk < 2; kk++)
      qf[grp][kk] = asbf(*(const u16x8*)(Qg + (size_t)row * 64 + kk * 32 + g * 8));
  }
  f32x4 oacc[2][4] = {};
  f32x4 acc_l[2] = {};
  const int pl0 = ((lane >> 4) & 1) * 32 + qrow;
  const int pl1 = pl0 + 16;
  const bool phi = (lane >> 5) & 1;
  STAGE(0, kt0);
  int buf = 0;
  for (int kt = kt0; kt < kt1; kt++) {
    __syncthreads();
    if (kt + 1 < kt1) STAGE(buf ^ 1, kt + 1);
    f32x4 s0[4] = {}, s1[4] = {};
#pragma unroll
    for (int kk = 0; kk < 2; kk++)
#pragma unroll
      for (int nf = 0; nf < 4; nf++) {
        bf16x8 kf = frag8(lK[buf], nf * 16 + qrow, kk * 4 + g);
        s0[nf] = mfma32(kf, qf[0][kk], s0[nf]);
        s1[nf] = mfma32(kf, qf[1][kk], s1[nf]);
      }
    uint32_t wA[8], wB[8];
#pragma unroll
    for (int nf = 0; nf < 4; nf++) {
      wA[nf * 2]     = pack2(__builtin_amdgcn_exp2f(s0[nf][0]), __builtin_amdgcn_exp2f(s0[nf][1]));
      wA[nf * 2 + 1] = pack2(__builtin_amdgcn_exp2f(s0[nf][2]), __builtin_amdgcn_exp2f(s0[nf][3]));
      wB[nf * 2]     = pack2(__builtin_amdgcn_exp2f(s1[nf][0]), __builtin_amdgcn_exp2f(s1[nf][1]));
      wB[nf * 2 + 1] = pack2(__builtin_amdgcn_exp2f(s1[nf][2]), __builtin_amdgcn_exp2f(s1[nf][3]));
    }
#pragma unroll
    for (int kk = 0; kk < 2; kk++) {
      uint32_t aA0 = (uint32_t)__shfl((int)wA[4 * kk + 0], pl0);
      uint32_t bA0 = (uint32_t)__shfl((int)wA[4 * kk + 2], pl0);
      uint32_t aA1 = (uint32_t)__shfl((int)wA[4 * kk + 1], pl0);
      uint32_t bA1 = (uint32_t)__shfl((int)wA[4 * kk + 3], pl0);
      uint32_t aA2 = (uint32_t)__shfl((int)wA[4 * kk + 0], pl1);
      uint32_t bA2 = (uint32_t)__shfl((int)wA[4 * kk + 2], pl1);
      uint32_t aA3 = (uint32_t)__shfl((int)wA[4 * kk + 1], pl1);
      uint32_t bA3 = (uint32_t)__shfl((int)wA[4 * kk + 3], pl1);
      u32x4 pA4;
      pA4[0] = phi ? bA0 : aA0;
      pA4[1] = phi ? bA1 : aA1;
      pA4[2] = phi ? bA2 : aA2;
      pA4[3] = phi ? bA3 : aA3;
      bf16x8 pa0 = __builtin_bit_cast(bf16x8, pA4);
      uint32_t aB0 = (uint32_t)__shfl((int)wB[4 * kk + 0], pl0);
      uint32_t bB0 = (uint32_t)__shfl((int)wB[4 * kk + 2], pl0);
      uint32_t aB1 = (uint32_t)__shfl((int)wB[4 * kk + 1], pl0);
      uint32_t bB1 = (uint32_t)__shfl((int)wB[4 * kk + 3], pl0);
      uint32_t aB2 = (uint32_t)__shfl((int)wB[4 * kk + 0], pl1);
      uint32_t bB2 = (uint32_t)__shfl((int)wB[4 * kk + 2], pl1);
      uint32_t aB3 = (uint32_t)__shfl((int)wB[4 * kk + 1], pl1);
      uint32_t bB3 = (uint32_t)__shfl((int)wB[4 * kk + 3], pl1);
      u32x4 pB4;
      pB4[0] = phi ? bB0 : aB0;
      pB4[1] = phi ? bB1 : aB1;
      pB4[2] = phi ? bB2 : aB2;
      pB4[3] = phi ? bB3 : aB3;
      bf16x8 pa1 = __builtin_bit_cast(bf16x8, pB4);
      acc_l[0] = mfma32(pa0, ones, acc_l[0]);
      acc_l[1] = mfma32(pa1, ones, acc_l[1]);
#pragma unroll
      for (int df = 0; df < 4; df++) {
        bf16x8 vf = frag8(lV[buf], df * 16 + qrow, kk * 4 + g);
        oacc[0][df] = mfma32(pa0, vf, oacc[0][df]);
        oacc[1][df] = mfma32(pa1, vf, oacc[1][df]);
      }
    }
    buf ^= 1;
  }
  uint16_t* Op = (split == 0) ? Op0 : (split == 1) ? Op1 : (split == 2) ? Op2 : Op3;
#pragma unroll
  for (int grp = 0; grp < 2; grp++)
    for (int df = 0; df < 4; df++)
      for (int r = 0; r < 4; r++) {
        int srow = q0 + grp * 64 + wave * 16 + g * 4 + r;
        int e = df * 16 + qrow;
        Op[((size_t)b * 2048 + srow) * 1024 + h * 64 + e] = f2bf(oacc[grp][df][r]);
      }
  if (qrow == 0) {
#pragma unroll
    for (int grp = 0; grp < 2; grp++)
      for (int r = 0; r < 4; r++) {
        int srow = q0 + grp * 64 + wave * 16 + g * 4 + r;
        lbuf[((size_t)(split * 2 + b) * 16 + h) * 2048 + srow] = acc_l[grp][r];
      }
  }
}

// ---------------- merge (attn2): 4-way ----------------
__global__ __launch_bounds__(256) void merge4_k(const uint16_t* __restrict__ O0,
                                                const uint16_t* __restrict__ O1,
                                                const uint16_t* __restrict__ O2,
                                                const uint16_t* __restrict__ O3,
                                                const float* __restrict__ lbuf,
                                                uint16_t* __restrict__ out) {
  int i = (blockIdx.x * 256 + threadIdx.x) * 8;
  int sg = i >> 10;
  int b = sg >> 11, s = sg & 2047;
  int h = (i & 1023) >> 6;
  float l = 0.f;
  for (int sp = 0; sp < 4; sp++)
    l += lbuf[((size_t)(sp * 2 + b) * 16 + h) * 2048 + s];
  float inv = 1.f / l;
  u16x8 o0 = *(const u16x8*)(O0 + i);
  u16x8 o1 = *(const u16x8*)(O1 + i);
  u16x8 o2 = *(const u16x8*)(O2 + i);
  u16x8 o3 = *(const u16x8*)(O3 + i);
  u16x8 o;
  for (int j = 0; j < 8; j++)
    o[j] = f2bf((bf2f(o0[j]) + bf2f(o1[j]) + bf2f(o2[j]) + bf2f(o3[j])) * inv);
  *(u16x8*)(out + i) = o;
}

// ---------------- FFN GEMM: C[M,N] = A[M,K] @ Bt[N,K]^T (+bias raw, relu), R8 dbuf ----------------
template <int RELU>
__global__ __launch_bounds__(256) void ff_k(const uint16_t* __restrict__ A,
                                            const uint16_t* __restrict__ Bt,
                                            const void* __restrict__ bias,
                                            uint16_t* __restrict__ C, int Kdim, int N,
                                            const uint32_t* __restrict__ flag) {
  __shared__ __attribute__((aligned(16))) uint16_t lA[2][128 * 64];
  __shared__ __attribute__((aligned(16))) uint16_t lB[2][128 * 64];
  const int isbf = (int)flag[0];
  const int tid = threadIdx.x, lane = tid & 63, wave = tid >> 6;
  const int g = lane >> 4;
  const int m0 = blockIdx.x * 128, n0 = blockIdx.y * 128;
  const int wm = wave >> 1, wn = wave & 1;
  f32x4 acc[4][4] = {};
  u16x8 ra[4], rb[4];
  const int row0 = tid >> 3, slot0 = tid & 7;
  auto loadT = [&](int kt) {
    for (int i = 0; i < 4; i++) {
      int row = row0 + i * 32;
      ra[i] = *(const u16x8*)(A + (size_t)(m0 + row) * Kdim + kt + slot0 * 8);
      rb[i] = *(const u16x8*)(Bt + (size_t)(n0 + row) * Kdim + kt + slot0 * 8);
    }
  };
  auto writeT = [&](int buf) {
    for (int i = 0; i < 4; i++) {
      int row = row0 + i * 32;
      *(u16x8*)&lA[buf][(row * 8 + swz(row, slot0)) * 8] = ra[i];
      *(u16x8*)&lB[buf][(row * 8 + swz(row, slot0)) * 8] = rb[i];
    }
  };
  loadT(0);
  writeT(0);
  int cur = 0;
  const int nit = Kdim >> 6;
  for (int it = 0; it < nit; it++) {
    const int more = (it < nit - 1);
    if (more) loadT((it + 1) * 64);
    __syncthreads();
    for (int kk = 0; kk < 2; kk++) {
      bf16x8 af[4], bfr[4];
      for (int fm = 0; fm < 4; fm++) af[fm] = frag8(lA[cur], wm * 64 + fm * 16 + (lane & 15), kk * 4 + g);
      for (int fn = 0; fn < 4; fn++) bfr[fn] = frag8(lB[cur], wn * 64 + fn * 16 + (lane & 15), kk * 4 + g);
      for (int fm = 0; fm < 4; fm++)
        for (int fn = 0; fn < 4; fn++)
          acc[fm][fn] = mfma32(af[fm], bfr[fn], acc[fm][fn]);
    }
    if (more) writeT(cur ^ 1);
    cur ^= 1;
  }
  for (int fm = 0; fm < 4; fm++)
    for (int fn = 0; fn < 4; fn++) {
      int col = n0 + wn * 64 + fn * 16 + (lane & 15);
      float bv = isbf ? bf2f(((const uint16_t*)bias)[col]) : ((const float*)bias)[col];
      for (int r = 0; r < 4; r++) {
        int row = m0 + wm * 64 + fm * 16 + g * 4 + r;
        float v = acc[fm][fn][r] + bv;
        if (RELU) v = fmaxf(v, 0.f);
        C[(size_t)row * N + col] = f2bf(v);
      }
    }
}

// ---------------- output store ----------------
__global__ __launch_bounds__(256) void store_k(const uint16_t* __restrict__ yb,
                                               void* __restrict__ out, int n,
                                               const uint32_t* __restrict__ flag) {
  const int isbf = (int)flag[0];
  const int stride = gridDim.x * 256 * 8;
  for (int i = (blockIdx.x * 256 + threadIdx.x) * 8; i < n; i += stride) {
    u16x8 v = *(const u16x8*)(yb + i);
    if (isbf) {
      *(u16x8*)((uint16_t*)out + i) = v;
    } else {
      float* of = (float*)out + i;
      for (int j = 0; j < 8; j++) of[j] = bf2f(v[j]);
    }
  }
}

extern "C" void kernel_launch(void* const* d_in, const int* in_sizes, int n_in,
                              void* d_out, int out_size, void* d_ws, size_t ws_size,
                              hipStream_t stream) {
  const void* de_x = d_in[0];
  const void* en_x = d_in[1];
  const void* mask = d_in[2];
  const void* Wq = d_in[3];
  const void* Wk = d_in[4];
  const void* Wv = d_in[5];
  const void* W1 = d_in[6];
  const void* b1 = d_in[7];
  const void* W2 = d_in[8];
  const void* b2 = d_in[9];

  uint16_t* ws = (uint16_t*)d_ws;
  const size_t M1 = (size_t)1 << 20;
  uint32_t* flag = (uint32_t*)ws;
  float* lbuf = (float*)(ws + 8192);           // [8][b-folded][16][2048] f32 = 1MB
  uint16_t* Wtq = ws + 1 * M1;                 // [3][16][64][1024] contiguous (Q scaled)
  uint16_t* W1t = ws + 4 * M1;                 // [2048][1024]
  uint16_t* W2t = ws + 6 * M1;                 // [1024][2048]
  uint16_t* de_c = ws + 8 * M1;                // f32 path only
  uint16_t* en_c = ws + 12 * M1;
  uint16_t* Qb  = ws + 16 * M1;                // [B,H,S,64]
  uint16_t* Kb  = ws + 20 * M1;
  uint16_t* Vtb = ws + 24 * M1;                // [B,H,64,S]
  uint16_t* h1  = ws + 28 * M1;
  uint16_t* h2  = ws + 32 * M1;
  uint16_t* ff1 = Qb;                          // reuse
  uint16_t* yb  = Vtb;                         // reuse
  // attn1 partials: de_c (dead after proj1), h2 (free until ff1), h1 (merge in-place)
  // attn2 partials: de_c, en_c (dead after proj2), h1 (dead after proj2), h2 (merge in-place)

  const int NX = 2 * 2048 * 1024;
  dim3 blk(256);

  probe_k<<<1, 1, 0, stream>>>((const uint32_t*)mask, flag);
  cvt_k<<<2048, blk, 0, stream>>>(de_x, de_c, NX, flag);   // no-op when bf16
  cvt_k<<<2048, blk, 0, stream>>>(en_x, en_c, NX, flag);   // no-op when bf16
  transpose_qkv_k<<<dim3(2, 32, 48), blk, 0, stream>>>(Wq, Wk, Wv, Wtq, flag);
  transpose_k<<<dim3(64, 32, 1), blk, 0, stream>>>(W1, W1t, 1024, 2048, 1.0f, flag);
  transpose_k<<<dim3(32, 64, 1), blk, 0, stream>>>(W2, W2t, 2048, 1024, 1.0f, flag);
  // MHA1: q=k=v=de_x, causal, balanced CHUNK=11 3-way split-K
  proj_k<<<dim3(32, 24), blk, 0, stream>>>(de_c, de_x, de_c, de_x, Wtq, Qb, Kb, Vtb, flag);
  attn1_k<<<dim3(63, 16, 2), blk, 0, stream>>>(Qb, Kb, Vtb, de_c, h2, h1, lbuf);
  merge3_k<<<2048, blk, 0, stream>>>(de_c, h2, h1, lbuf, h1);
  // MHA2: q=k=en_x, v=h1, no mask, dual-group 4-way split-K
  proj_k<<<dim3(32, 24), blk, 0, stream>>>(en_c, en_x, h1, h1, Wtq, Qb, Kb, Vtb, flag);
  attn2_k<<<dim3(64, 16, 2), blk, 0, stream>>>(Qb, Kb, Vtb, de_c, en_c, h1, h2, lbuf);
  merge4_k<<<2048, blk, 0, stream>>>(de_c, en_c, h1, h2, lbuf, h2);
  // FFN (biases read raw, flag-selected)
  ff_k<1><<<dim3(32, 16), blk, 0, stream>>>(h2, W1t, b1, ff1, 1024, 2048, flag);
  ff_k<0><<<dim3(32, 8), blk, 0, stream>>>(ff1, W2t, b2, yb, 2048, 1024, flag);
  store_k<<<2048, blk, 0, stream>>>(yb, d_out, out_size, flag);
}

// Round 17
// 266.140 us; speedup vs baseline: 1.0586x; 1.0586x over previous
//
#include <hip/hip_runtime.h>
#include <stdint.h>

// DecoderLayer: B=2, S=2048, DIM=1024, H=16, DH=64, DFF=2048
// Round 17: revert to R15 (measured best, 264.8us). R16's shfl-P regressed
// (ds_bpermute doubles LDS crossbar conflicts). attn1: single-group causal,
// CHUNK=11 3-way balanced split. attn2: dual-group 4-way. GEMMs: R8 dbuf.

#define DEV static __device__ __forceinline__

typedef __attribute__((ext_vector_type(8))) __bf16 bf16x8;           // MFMA A/B
typedef __attribute__((ext_vector_type(8))) unsigned short u16x8;
typedef __attribute__((ext_vector_type(2))) uint32_t u32x2;
typedef __attribute__((ext_vector_type(4))) float f32x4;

DEV float bf2f(uint16_t u) { union { uint32_t u; float f; } v; v.u = ((uint32_t)u) << 16; return v.f; }
DEV uint16_t f2bf(float f) {
  union { float f; uint32_t u; } v; v.f = f;
  uint32_t r = v.u + 0x7fffu + ((v.u >> 16) & 1u);
  return (uint16_t)(r >> 16);
}
DEV uint16_t f2bf_hw(float f) { return __builtin_bit_cast(unsigned short, (__bf16)f); }

DEV bf16x8 asbf(u16x8 v) { return __builtin_bit_cast(bf16x8, v); }
DEV f32x4 mfma32(bf16x8 a, bf16x8 b, f32x4 c) {
  return __builtin_amdgcn_mfma_f32_16x16x32_bf16(a, b, c, 0, 0, 0);
}

// async global->LDS, 16B per lane (attn staging).
DEV void gload_lds16(const void* g, void* l) {
  __builtin_amdgcn_global_load_lds(
      (const __attribute__((address_space(1))) uint32_t*)g,
      (__attribute__((address_space(3))) uint32_t*)l, 16, 0, 0);
}

// XOR swizzle: 16B slot s of row r <-> slot s^(r&7). Rows are 64 bf16 = 128B.
DEV int swz(int row, int slot) { return slot ^ (row & 7); }

DEV bf16x8 frag8(const uint16_t* l, int row, int slot) {
  u16x8 v = *(const u16x8*)((const char*)l + row * 128 + (swz(row, slot) << 4));
  return asbf(v);
}

// attn1 block decode tables: 63 blocks per (h,b); qt desc (longest chains first)
__constant__ uint8_t QT_TAB[63] = {
  31,31,31,30,30,30,29,29,29,28,28,28,27,27,27,26,26,26,25,25,25,24,24,24,
  23,23,23,22,22,22,
  21,21,20,20,19,19,18,18,17,17,16,16,15,15,14,14,13,13,12,12,11,11,
  10,9,8,7,6,5,4,3,2,1,0};
__constant__ uint8_t SP_TAB[63] = {
  0,1,2,0,1,2,0,1,2,0,1,2,0,1,2,0,1,2,0,1,2,0,1,2,
  0,1,2,0,1,2,
  0,1,0,1,0,1,0,1,0,1,0,1,0,1,0,1,0,1,0,1,0,1,
  0,0,0,0,0,0,0,0,0,0,0};

// ---------------- dtype probe ----------------
__global__ void probe_k(const uint32_t* __restrict__ mask, uint32_t* __restrict__ flag) {
  flag[0] = (mask[1] & 0xFFFFu) ? 1u : 0u;   // 1 = bf16, 0 = f32
}

// ---------------- ingest convert (f32 path only; no-op when bf16) ----------------
__global__ __launch_bounds__(256) void cvt_k(const void* __restrict__ src,
                                             uint16_t* __restrict__ dst, int n,
                                             const uint32_t* __restrict__ flag) {
  if (flag[0]) return;
  const int stride = gridDim.x * 256 * 8;
  for (int i = (blockIdx.x * 256 + threadIdx.x) * 8; i < n; i += stride) {
    const float* sf = (const float*)src + i;
    u16x8 o;
    for (int j = 0; j < 8; j++) o[j] = f2bf(sf[j]);
    *(u16x8*)(dst + i) = o;
  }
}

// ---------------- generic transpose+convert+scale: in[b][R][C] -> out[b][C][R] ----------------
__global__ __launch_bounds__(256) void transpose_k(const void* __restrict__ in_,
                                                   uint16_t* __restrict__ out, int R, int C,
                                                   float scale,
                                                   const uint32_t* __restrict__ flag) {
  __shared__ uint16_t t[32][33];
  const int isbf = (int)flag[0];
  const int b = blockIdx.z;
  const float* in_f = (const float*)in_ + (size_t)b * R * C;
  const uint16_t* in_u = (const uint16_t*)in_ + (size_t)b * R * C;
  out += (size_t)b * R * C;
  const int c0 = blockIdx.x * 32, r0 = blockIdx.y * 32;
  const int tx = threadIdx.x & 31, ty = threadIdx.x >> 5;
  for (int i = 0; i < 4; i++) {
    int r = ty + i * 8;
    size_t idx = (size_t)(r0 + r) * C + c0 + tx;
    uint16_t v;
    if (isbf) v = (scale == 1.0f) ? in_u[idx] : f2bf(bf2f(in_u[idx]) * scale);
    else      v = f2bf(in_f[idx] * scale);
    t[r][tx] = v;
  }
  __syncthreads();
  for (int i = 0; i < 4; i++) {
    int r = ty + i * 8;
    out[(size_t)(c0 + r) * R + r0 + tx] = t[tx][r];
  }
}

// ---------------- fused QKV weight transpose: Wq/Wk/Wv [16][1024][64] -> Wt[3072][1024] ----------------
__global__ __launch_bounds__(256) void transpose_qkv_k(const void* __restrict__ Wq,
                                                       const void* __restrict__ Wk,
                                                       const void* __restrict__ Wv,
                                                       uint16_t* __restrict__ out,
                                                       const uint32_t* __restrict__ flag) {
  __shared__ uint16_t t[32][33];
  const int isbf = (int)flag[0];
  const int which = blockIdx.z >> 4, hh = blockIdx.z & 15;
  const void* in_ = (which == 0 ? Wq : which == 1 ? Wk : Wv);
  const float scale = (which == 0) ? 0.180336880f : 1.0f;   // 0.125*log2(e)
  const int R = 1024, C = 64;
  const float* in_f = (const float*)in_ + (size_t)hh * R * C;
  const uint16_t* in_u = (const uint16_t*)in_ + (size_t)hh * R * C;
  out += ((size_t)which * 16 + hh) * R * C;
  const int c0 = blockIdx.x * 32, r0 = blockIdx.y * 32;
  const int tx = threadIdx.x & 31, ty = threadIdx.x >> 5;
  for (int i = 0; i < 4; i++) {
    int r = ty + i * 8;
    size_t idx = (size_t)(r0 + r) * C + c0 + tx;
    uint16_t v;
    if (isbf) v = (scale == 1.0f) ? in_u[idx] : f2bf(bf2f(in_u[idx]) * scale);
    else      v = f2bf(in_f[idx] * scale);
    t[r][tx] = v;
  }
  __syncthreads();
  for (int i = 0; i < 4; i++) {
    int r = ty + i * 8;
    out[(size_t)(c0 + r) * R + r0 + tx] = t[tx][r];
  }
}

// ---------------- fused QKV projection: C[4096][3072] = A @ Wt^T (R8 structure) ----------------
__global__ __launch_bounds__(256) void proj_k(
    const uint16_t* __restrict__ Aqk_c, const void* __restrict__ Aqk_r,
    const uint16_t* __restrict__ Av_c, const void* __restrict__ Av_r,
    const uint16_t* __restrict__ Wt,
    uint16_t* __restrict__ Q, uint16_t* __restrict__ K, uint16_t* __restrict__ Vt,
    const uint32_t* __restrict__ flag) {
  __shared__ __attribute__((aligned(16))) uint16_t lA[2][128 * 64];
  __shared__ __attribute__((aligned(16))) uint16_t lB[2][128 * 64];
  const int isbf = (int)flag[0];
  const uint16_t* Aqk = isbf ? (const uint16_t*)Aqk_r : Aqk_c;
  const uint16_t* Av  = isbf ? (const uint16_t*)Av_r  : Av_c;
  const int tid = threadIdx.x, lane = tid & 63, wave = tid >> 6;
  const int g = lane >> 4;
  const int m0 = blockIdx.x * 128, n0 = blockIdx.y * 128;
  const int proj = n0 >> 10;
  const uint16_t* A = (proj == 2 ? Av : Aqk);
  const uint16_t* Bt = Wt + (size_t)n0 * 1024;
  const int wm = wave >> 1, wn = wave & 1;
  f32x4 acc[4][4] = {};
  u16x8 ra[4], rb[4];
  const int row0 = tid >> 3, slot0 = tid & 7;
  auto loadT = [&](int kt) {
    for (int i = 0; i < 4; i++) {
      int row = row0 + i * 32;
      ra[i] = *(const u16x8*)(A + (size_t)(m0 + row) * 1024 + kt + slot0 * 8);
      rb[i] = *(const u16x8*)(Bt + (size_t)row * 1024 + kt + slot0 * 8);
    }
  };
  auto writeT = [&](int buf) {
    for (int i = 0; i < 4; i++) {
      int row = row0 + i * 32;
      *(u16x8*)&lA[buf][(row * 8 + swz(row, slot0)) * 8] = ra[i];
      *(u16x8*)&lB[buf][(row * 8 + swz(row, slot0)) * 8] = rb[i];
    }
  };
  loadT(0);
  writeT(0);
  int cur = 0;
  for (int it = 0; it < 16; it++) {
    const int more = (it < 15);
    if (more) loadT((it + 1) * 64);
    __syncthreads();
    for (int kk = 0; kk < 2; kk++) {
      bf16x8 af[4], bfr[4];
      for (int fm = 0; fm < 4; fm++) af[fm] = frag8(lA[cur], wm * 64 + fm * 16 + (lane & 15), kk * 4 + g);
      for (int fn = 0; fn < 4; fn++) bfr[fn] = frag8(lB[cur], wn * 64 + fn * 16 + (lane & 15), kk * 4 + g);
      for (int fm = 0; fm < 4; fm++)
        for (int fn = 0; fn < 4; fn++)
          acc[fm][fn] = mfma32(af[fm], bfr[fn], acc[fm][fn]);
    }
    if (more) writeT(cur ^ 1);
    cur ^= 1;
  }
  if (proj != 2) {
    uint16_t* outp = (proj == 0 ? Q : K);
    for (int fm = 0; fm < 4; fm++)
      for (int fn = 0; fn < 4; fn++)
        for (int r = 0; r < 4; r++) {
          int row = m0 + wm * 64 + fm * 16 + g * 4 + r;
          int b = row >> 11, s = row & 2047;
          int col = n0 + wn * 64 + fn * 16 + (lane & 15);
          int h = (col >> 6) & 15, e = col & 63;
          outp[(((size_t)(b * 16 + h)) * 2048 + s) * 64 + e] = f2bf(acc[fm][fn][r]);
        }
  } else {
    __syncthreads();
    uint16_t* tv = (uint16_t*)lA;   // 32 KB: 128 cols x 256B
    for (int fm = 0; fm < 4; fm++)
      for (int fn = 0; fn < 4; fn++)
        for (int r = 0; r < 4; r++) {
          int rl = wm * 64 + fm * 16 + g * 4 + r;
          int cl = wn * 64 + fn * 16 + (lane & 15);
          int byte = rl * 2;
          *(uint16_t*)((char*)tv + cl * 256 + ((((byte >> 4)) ^ (cl & 15)) << 4) + (byte & 15)) =
              f2bf(acc[fm][fn][r]);
        }
    __syncthreads();
    const int b = m0 >> 11, s0 = m0 & 2047;
    const int c = tid >> 1, half = tid & 1;
    const int col = n0 + c;
    const int h = (col >> 6) & 15, e = col & 63;
    uint16_t* dst = Vt + (((size_t)(b * 16 + h)) * 64 + e) * 2048 + s0 + half * 64;
    for (int j = 0; j < 8; j++) {
      int rl = half * 64 + j * 8;
      u16x8 v = *(const u16x8*)((const char*)tv + c * 256 + (((rl >> 3) ^ (c & 15)) << 4));
      *(u16x8*)(dst + j * 8) = v;
    }
  }
}

// ---------------- causal flash attention: single-group, CHUNK=11, 3-way, no empties ----------------
// grid (63, 16, 2). (qt, split) from QT_TAB/SP_TAB; tiles [11*split, min(+11, qt+1)).
__global__ __launch_bounds__(256) void attn1_k(const uint16_t* __restrict__ Q,
                                               const uint16_t* __restrict__ K,
                                               const uint16_t* __restrict__ Vt,
                                               uint16_t* __restrict__ Op0,
                                               uint16_t* __restrict__ Op1,
                                               uint16_t* __restrict__ Op2,
                                               float* __restrict__ lbuf) {
  __shared__ __attribute__((aligned(16))) uint16_t lK[2][64 * 64];
  __shared__ __attribute__((aligned(16))) uint16_t lV[2][64 * 64];
  __shared__ __attribute__((aligned(16))) uint16_t lP[4][16 * 64];
  const int tid = threadIdx.x, lane = tid & 63, wave = tid >> 6;
  const int g = lane >> 4, qrow = lane & 15;
  const int bx = blockIdx.x, h = blockIdx.y, b = blockIdx.z;
  const int qt = QT_TAB[bx], split = SP_TAB[bx];
  const int kt0 = split * 11;
  const int lim = qt + 1;
  const int kt1 = (kt0 + 11 < lim) ? kt0 + 11 : lim;
  const size_t bh = (size_t)(b * 16 + h);
  const uint16_t* Qg = Q + bh * 2048 * 64;
  const uint16_t* Kg = K + bh * 2048 * 64;
  const uint16_t* Vg = Vt + bh * 64 * 2048;
  uint16_t* lPw = lP[wave];
  bf16x8 ones;
  for (int j = 0; j < 8; j++) ones[j] = (__bf16)1.0f;
  const int lrow = lane >> 3, sl = lane & 7;
  auto STAGE = [&](int buf, int kt) {
    for (int i = 0; i < 2; i++) {
      int cb = (i * 4 + wave) * 64;
      int row = (cb >> 3) + lrow;
      int so = swz(row, sl) << 3;
      gload_lds16(Kg + (size_t)(kt * 64 + row) * 64 + so, &lK[buf][cb * 8]);
      gload_lds16(Vg + (size_t)row * 2048 + kt * 64 + so, &lV[buf][cb * 8]);
    }
  };
  const int q0 = qt * 64;
  bf16x8 qf[2];
  {
    int row = q0 + wave * 16 + qrow;
    for (int kk = 0; kk < 2; kk++)
      qf[kk] = asbf(*(const u16x8*)(Qg + (size_t)row * 64 + kk * 32 + g * 8));
  }
  f32x4 oacc[4] = {};
  f32x4 acc_l = {};
  STAGE(0, kt0);
  int buf = 0;
  for (int kt = kt0; kt < kt1; kt++) {
    __syncthreads();
    if (kt + 1 < kt1) STAGE(buf ^ 1, kt + 1);
    f32x4 s[4] = {};
    for (int kk = 0; kk < 2; kk++)
      for (int nf = 0; nf < 4; nf++)
        s[nf] = mfma32(frag8(lK[buf], nf * 16 + qrow, kk * 4 + g), qf[kk], s[nf]);
    if (kt == qt) {
      for (int nf = 0; nf < 4; nf++)
        for (int r = 0; r < 4; r++) {
          int kloc = nf * 16 + g * 4 + r;
          if (kloc > wave * 16 + qrow) s[nf][r] = -1e9f;
        }
    }
    for (int nf = 0; nf < 4; nf++) {
      float p0 = __builtin_amdgcn_exp2f(s[nf][0]);
      float p1 = __builtin_amdgcn_exp2f(s[nf][1]);
      float p2 = __builtin_amdgcn_exp2f(s[nf][2]);
      float p3 = __builtin_amdgcn_exp2f(s[nf][3]);
      u32x2 w;
      w[0] = ((uint32_t)f2bf_hw(p1) << 16) | f2bf_hw(p0);
      w[1] = ((uint32_t)f2bf_hw(p3) << 16) | f2bf_hw(p2);
      int slot = 2 * nf + (g >> 1);
      *(u32x2*)((char*)lPw + qrow * 128 + ((slot ^ (qrow & 7)) << 4) + ((g & 1) << 3)) = w;
    }
    for (int kk = 0; kk < 2; kk++) {
      bf16x8 pa = frag8(lPw, qrow, kk * 4 + g);
      acc_l = mfma32(pa, ones, acc_l);
      for (int df = 0; df < 4; df++)
        oacc[df] = mfma32(pa, frag8(lV[buf], df * 16 + qrow, kk * 4 + g), oacc[df]);
    }
    buf ^= 1;
  }
  uint16_t* Op = (split == 0) ? Op0 : (split == 1) ? Op1 : Op2;
  for (int df = 0; df < 4; df++)
    for (int r = 0; r < 4; r++) {
      int srow = q0 + wave * 16 + g * 4 + r;
      int e = df * 16 + qrow;
      Op[((size_t)b * 2048 + srow) * 1024 + h * 64 + e] = f2bf(oacc[df][r]);
    }
  if (qrow == 0) {
    for (int r = 0; r < 4; r++) {
      int srow = q0 + wave * 16 + g * 4 + r;
      lbuf[((size_t)(split * 2 + b) * 16 + h) * 2048 + srow] = acc_l[r];
    }
  }
}

// ---------------- merge (attn1): conditional 1/2/3-way by qt ----------------
__global__ __launch_bounds__(256) void merge3_k(const uint16_t* __restrict__ O0,
                                                const uint16_t* __restrict__ O1,
                                                const uint16_t* __restrict__ O2,
                                                const float* __restrict__ lbuf,
                                                uint16_t* __restrict__ out) {
  int i = (blockIdx.x * 256 + threadIdx.x) * 8;
  int sg = i >> 10;
  int b = sg >> 11, s = sg & 2047;
  int h = (i & 1023) >> 6;
  const int qt = s >> 6;
  const int nch = (qt + 11) / 11;               // ceil((qt+1)/11)
  float l = lbuf[((size_t)b * 16 + h) * 2048 + s];
  u16x8 o0 = *(const u16x8*)(O0 + i);
  float acc[8];
  for (int j = 0; j < 8; j++) acc[j] = bf2f(o0[j]);
  if (nch >= 2) {
    l += lbuf[((size_t)(2 + b) * 16 + h) * 2048 + s];
    u16x8 o1 = *(const u16x8*)(O1 + i);
    for (int j = 0; j < 8; j++) acc[j] += bf2f(o1[j]);
  }
  if (nch >= 3) {
    l += lbuf[((size_t)(4 + b) * 16 + h) * 2048 + s];
    u16x8 o2 = *(const u16x8*)(O2 + i);
    for (int j = 0; j < 8; j++) acc[j] += bf2f(o2[j]);
  }
  float inv = 1.f / l;
  u16x8 o;
  for (int j = 0; j < 8; j++) o[j] = f2bf(acc[j] * inv);
  *(u16x8*)(out + i) = o;
}

// ---------------- non-causal flash attention: dual-group (128 q/block), 4-way split ----------------
__global__ __launch_bounds__(256) void attn2_k(const uint16_t* __restrict__ Q,
                                               const uint16_t* __restrict__ K,
                                               const uint16_t* __restrict__ Vt,
                                               uint16_t* __restrict__ Op0,
                                               uint16_t* __restrict__ Op1,
                                               uint16_t* __restrict__ Op2,
                                               uint16_t* __restrict__ Op3,
                                               float* __restrict__ lbuf) {
  __shared__ __attribute__((aligned(16))) uint16_t lK[2][64 * 64];
  __shared__ __attribute__((aligned(16))) uint16_t lV[2][64 * 64];
  __shared__ __attribute__((aligned(16))) uint16_t lP[8][16 * 64];
  const int tid = threadIdx.x, lane = tid & 63, wave = tid >> 6;
  const int g = lane >> 4, qrow = lane & 15;
  const int bx = blockIdx.x, h = blockIdx.y, b = blockIdx.z;
  const int pair = bx >> 2, split = bx & 3;
  const int kt0 = split * 8, kt1 = kt0 + 8;
  const int q0 = pair * 128;
  const size_t bh = (size_t)(b * 16 + h);
  const uint16_t* Qg = Q + bh * 2048 * 64;
  const uint16_t* Kg = K + bh * 2048 * 64;
  const uint16_t* Vg = Vt + bh * 64 * 2048;
  uint16_t* lP0 = lP[wave * 2];
  uint16_t* lP1 = lP[wave * 2 + 1];
  bf16x8 ones;
  for (int j = 0; j < 8; j++) ones[j] = (__bf16)1.0f;
  const int lrow = lane >> 3, sl = lane & 7;
  auto STAGE = [&](int buf, int kt) {
    for (int i = 0; i < 2; i++) {
      int cb = (i * 4 + wave) * 64;
      int row = (cb >> 3) + lrow;
      int so = swz(row, sl) << 3;
      gload_lds16(Kg + (size_t)(kt * 64 + row) * 64 + so, &lK[buf][cb * 8]);
      gload_lds16(Vg + (size_t)row * 2048 + kt * 64 + so, &lV[buf][cb * 8]);
    }
  };
  bf16x8 qf[2][2];
#pragma unroll
  for (int grp = 0; grp < 2; grp++) {
    int row = q0 + grp * 64 + wave * 16 + qrow;
    for (int kk = 0; kk < 2; kk++)
      qf[grp][kk] = asbf(*(const u16x8*)(Qg + (size_t)row * 64 + kk * 32 + g * 8));
  }
  f32x4 oacc[2][4] = {};
  f32x4 acc_l[2] = {};
  auto storeP = [&](uint16_t* lPw, f32x4 (&s)[4]) {
#pragma unroll
    for (int nf = 0; nf < 4; nf++) {
      float p0 = __builtin_amdgcn_exp2f(s[nf][0]);
      float p1 = __builtin_amdgcn_exp2f(s[nf][1]);
      float p2 = __builtin_amdgcn_exp2f(s[nf][2]);
      float p3 = __builtin_amdgcn_exp2f(s[nf][3]);
      u32x2 w;
      w[0] = ((uint32_t)f2bf_hw(p1) << 16) | f2bf_hw(p0);
      w[1] = ((uint32_t)f2bf_hw(p3) << 16) | f2bf_hw(p2);
      int slot = 2 * nf + (g >> 1);
      *(u32x2*)((char*)lPw + qrow * 128 + ((slot ^ (qrow & 7)) << 4) + ((g & 1) << 3)) = w;
    }
  };
  STAGE(0, kt0);
  int buf = 0;
  for (int kt = kt0; kt < kt1; kt++) {
    __syncthreads();
    if (kt + 1 < kt1) STAGE(buf ^ 1, kt + 1);
    f32x4 s0[4] = {}, s1[4] = {};
#pragma unroll
    for (int kk = 0; kk < 2; kk++)
#pragma unroll
      for (int nf = 0; nf < 4; nf++) {
        bf16x8 kf = frag8(lK[buf], nf * 16 + qrow, kk * 4 + g);
        s0[nf] = mfma32(kf, qf[0][kk], s0[nf]);
        s1[nf] = mfma32(kf, qf[1][kk], s1[nf]);
      }
    storeP(lP0, s0);
    storeP(lP1, s1);
#pragma unroll
    for (int kk = 0; kk < 2; kk++) {
      bf16x8 pa0 = frag8(lP0, qrow, kk * 4 + g);
      bf16x8 pa1 = frag8(lP1, qrow, kk * 4 + g);
      acc_l[0] = mfma32(pa0, ones, acc_l[0]);
      acc_l[1] = mfma32(pa1, ones, acc_l[1]);
#pragma unroll
      for (int df = 0; df < 4; df++) {
        bf16x8 vf = frag8(lV[buf], df * 16 + qrow, kk * 4 + g);
        oacc[0][df] = mfma32(pa0, vf, oacc[0][df]);
        oacc[1][df] = mfma32(pa1, vf, oacc[1][df]);
      }
    }
    buf ^= 1;
  }
  uint16_t* Op = (split == 0) ? Op0 : (split == 1) ? Op1 : (split == 2) ? Op2 : Op3;
#pragma unroll
  for (int grp = 0; grp < 2; grp++)
    for (int df = 0; df < 4; df++)
      for (int r = 0; r < 4; r++) {
        int srow = q0 + grp * 64 + wave * 16 + g * 4 + r;
        int e = df * 16 + qrow;
        Op[((size_t)b * 2048 + srow) * 1024 + h * 64 + e] = f2bf(oacc[grp][df][r]);
      }
  if (qrow == 0) {
#pragma unroll
    for (int grp = 0; grp < 2; grp++)
      for (int r = 0; r < 4; r++) {
        int srow = q0 + grp * 64 + wave * 16 + g * 4 + r;
        lbuf[((size_t)(split * 2 + b) * 16 + h) * 2048 + srow] = acc_l[grp][r];
      }
  }
}

// ---------------- merge (attn2): 4-way ----------------
__global__ __launch_bounds__(256) void merge4_k(const uint16_t* __restrict__ O0,
                                                const uint16_t* __restrict__ O1,
                                                const uint16_t* __restrict__ O2,
                                                const uint16_t* __restrict__ O3,
                                                const float* __restrict__ lbuf,
                                                uint16_t* __restrict__ out) {
  int i = (blockIdx.x * 256 + threadIdx.x) * 8;
  int sg = i >> 10;
  int b = sg >> 11, s = sg & 2047;
  int h = (i & 1023) >> 6;
  float l = 0.f;
  for (int sp = 0; sp < 4; sp++)
    l += lbuf[((size_t)(sp * 2 + b) * 16 + h) * 2048 + s];
  float inv = 1.f / l;
  u16x8 o0 = *(const u16x8*)(O0 + i);
  u16x8 o1 = *(const u16x8*)(O1 + i);
  u16x8 o2 = *(const u16x8*)(O2 + i);
  u16x8 o3 = *(const u16x8*)(O3 + i);
  u16x8 o;
  for (int j = 0; j < 8; j++)
    o[j] = f2bf((bf2f(o0[j]) + bf2f(o1[j]) + bf2f(o2[j]) + bf2f(o3[j])) * inv);
  *(u16x8*)(out + i) = o;
}

// ---------------- FFN GEMM: C[M,N] = A[M,K] @ Bt[N,K]^T (+bias raw, relu), R8 dbuf ----------------
template <int RELU>
__global__ __launch_bounds__(256) void ff_k(const uint16_t* __restrict__ A,
                                            const uint16_t* __restrict__ Bt,
                                            const void* __restrict__ bias,
                                            uint16_t* __restrict__ C, int Kdim, int N,
                                            const uint32_t* __restrict__ flag) {
  __shared__ __attribute__((aligned(16))) uint16_t lA[2][128 * 64];
  __shared__ __attribute__((aligned(16))) uint16_t lB[2][128 * 64];
  const int isbf = (int)flag[0];
  const int tid = threadIdx.x, lane = tid & 63, wave = tid >> 6;
  const int g = lane >> 4;
  const int m0 = blockIdx.x * 128, n0 = blockIdx.y * 128;
  const int wm = wave >> 1, wn = wave & 1;
  f32x4 acc[4][4] = {};
  u16x8 ra[4], rb[4];
  const int row0 = tid >> 3, slot0 = tid & 7;
  auto loadT = [&](int kt) {
    for (int i = 0; i < 4; i++) {
      int row = row0 + i * 32;
      ra[i] = *(const u16x8*)(A + (size_t)(m0 + row) * Kdim + kt + slot0 * 8);
      rb[i] = *(const u16x8*)(Bt + (size_t)(n0 + row) * Kdim + kt + slot0 * 8);
    }
  };
  auto writeT = [&](int buf) {
    for (int i = 0; i < 4; i++) {
      int row = row0 + i * 32;
      *(u16x8*)&lA[buf][(row * 8 + swz(row, slot0)) * 8] = ra[i];
      *(u16x8*)&lB[buf][(row * 8 + swz(row, slot0)) * 8] = rb[i];
    }
  };
  loadT(0);
  writeT(0);
  int cur = 0;
  const int nit = Kdim >> 6;
  for (int it = 0; it < nit; it++) {
    const int more = (it < nit - 1);
    if (more) loadT((it + 1) * 64);
    __syncthreads();
    for (int kk = 0; kk < 2; kk++) {
      bf16x8 af[4], bfr[4];
      for (int fm = 0; fm < 4; fm++) af[fm] = frag8(lA[cur], wm * 64 + fm * 16 + (lane & 15), kk * 4 + g);
      for (int fn = 0; fn < 4; fn++) bfr[fn] = frag8(lB[cur], wn * 64 + fn * 16 + (lane & 15), kk * 4 + g);
      for (int fm = 0; fm < 4; fm++)
        for (int fn = 0; fn < 4; fn++)
          acc[fm][fn] = mfma32(af[fm], bfr[fn], acc[fm][fn]);
    }
    if (more) writeT(cur ^ 1);
    cur ^= 1;
  }
  for (int fm = 0; fm < 4; fm++)
    for (int fn = 0; fn < 4; fn++) {
      int col = n0 + wn * 64 + fn * 16 + (lane & 15);
      float bv = isbf ? bf2f(((const uint16_t*)bias)[col]) : ((const float*)bias)[col];
      for (int r = 0; r < 4; r++) {
        int row = m0 + wm * 64 + fm * 16 + g * 4 + r;
        float v = acc[fm][fn][r] + bv;
        if (RELU) v = fmaxf(v, 0.f);
        C[(size_t)row * N + col] = f2bf(v);
      }
    }
}

// ---------------- output store ----------------
__global__ __launch_bounds__(256) void store_k(const uint16_t* __restrict__ yb,
                                               void* __restrict__ out, int n,
                                               const uint32_t* __restrict__ flag) {
  const int isbf = (int)flag[0];
  const int stride = gridDim.x * 256 * 8;
  for (int i = (blockIdx.x * 256 + threadIdx.x) * 8; i < n; i += stride) {
    u16x8 v = *(const u16x8*)(yb + i);
    if (isbf) {
      *(u16x8*)((uint16_t*)out + i) = v;
    } else {
      float* of = (float*)out + i;
      for (int j = 0; j < 8; j++) of[j] = bf2f(v[j]);
    }
  }
}

extern "C" void kernel_launch(void* const* d_in, const int* in_sizes, int n_in,
                              void* d_out, int out_size, void* d_ws, size_t ws_size,
                              hipStream_t stream) {
  const void* de_x = d_in[0];
  const void* en_x = d_in[1];
  const void* mask = d_in[2];
  const void* Wq = d_in[3];
  const void* Wk = d_in[4];
  const void* Wv = d_in[5];
  const void* W1 = d_in[6];
  const void* b1 = d_in[7];
  const void* W2 = d_in[8];
  const void* b2 = d_in[9];

  uint16_t* ws = (uint16_t*)d_ws;
  const size_t M1 = (size_t)1 << 20;
  uint32_t* flag = (uint32_t*)ws;
  float* lbuf = (float*)(ws + 8192);           // [8][b-folded][16][2048] f32 = 1MB
  uint16_t* Wtq = ws + 1 * M1;                 // [3][16][64][1024] contiguous (Q scaled)
  uint16_t* W1t = ws + 4 * M1;                 // [2048][1024]
  uint16_t* W2t = ws + 6 * M1;                 // [1024][2048]
  uint16_t* de_c = ws + 8 * M1;                // f32 path only
  uint16_t* en_c = ws + 12 * M1;
  uint16_t* Qb  = ws + 16 * M1;                // [B,H,S,64]
  uint16_t* Kb  = ws + 20 * M1;
  uint16_t* Vtb = ws + 24 * M1;                // [B,H,64,S]
  uint16_t* h1  = ws + 28 * M1;
  uint16_t* h2  = ws + 32 * M1;
  uint16_t* ff1 = Qb;                          // reuse
  uint16_t* yb  = Vtb;                         // reuse
  // attn1 partials: de_c (dead after proj1), h2 (free until ff1), h1 (merge in-place)
  // attn2 partials: de_c, en_c (dead after proj2), h1 (dead after proj2), h2 (merge in-place)

  const int NX = 2 * 2048 * 1024;
  dim3 blk(256);

  probe_k<<<1, 1, 0, stream>>>((const uint32_t*)mask, flag);
  cvt_k<<<2048, blk, 0, stream>>>(de_x, de_c, NX, flag);   // no-op when bf16
  cvt_k<<<2048, blk, 0, stream>>>(en_x, en_c, NX, flag);   // no-op when bf16
  transpose_qkv_k<<<dim3(2, 32, 48), blk, 0, stream>>>(Wq, Wk, Wv, Wtq, flag);
  transpose_k<<<dim3(64, 32, 1), blk, 0, stream>>>(W1, W1t, 1024, 2048, 1.0f, flag);
  transpose_k<<<dim3(32, 64, 1), blk, 0, stream>>>(W2, W2t, 2048, 1024, 1.0f, flag);
  // MHA1: q=k=v=de_x, causal, balanced CHUNK=11 3-way split-K
  proj_k<<<dim3(32, 24), blk, 0, stream>>>(de_c, de_x, de_c, de_x, Wtq, Qb, Kb, Vtb, flag);
  attn1_k<<<dim3(63, 16, 2), blk, 0, stream>>>(Qb, Kb, Vtb, de_c, h2, h1, lbuf);
  merge3_k<<<2048, blk, 0, stream>>>(de_c, h2, h1, lbuf, h1);
  // MHA2: q=k=en_x, v=h1, no mask, dual-group 4-way split-K
  proj_k<<<dim3(32, 24), blk, 0, stream>>>(en_c, en_x, h1, h1, Wtq, Qb, Kb, Vtb, flag);
  attn2_k<<<dim3(64, 16, 2), blk, 0, stream>>>(Qb, Kb, Vtb, de_c, en_c, h1, h2, lbuf);
  merge4_k<<<2048, blk, 0, stream>>>(de_c, en_c, h1, h2, lbuf, h2);
  // FFN (biases read raw, flag-selected)
  ff_k<1><<<dim3(32, 16), blk, 0, stream>>>(h2, W1t, b1, ff1, 1024, 2048, flag);
  ff_k<0><<<dim3(32, 8), blk, 0, stream>>>(ff1, W2t, b2, yb, 2048, 1024, flag);
  store_k<<<2048, blk, 0, stream>>>(yb, d_out, out_size, flag);
}

// Round 18
// 258.137 us; speedup vs baseline: 1.0914x; 1.0310x over previous
//
#include <hip/hip_runtime.h>
#include <stdint.h>

// DecoderLayer: B=2, S=2048, DIM=1024, H=16, DH=64, DFF=2048
// Round 18: R17/R15 structure (measured best) + ff2 writes d_out directly
// (flag-dtyped epilogue) -> store_k launch and 16MB yb round-trip removed.

#define DEV static __device__ __forceinline__

typedef __attribute__((ext_vector_type(8))) __bf16 bf16x8;           // MFMA A/B
typedef __attribute__((ext_vector_type(8))) unsigned short u16x8;
typedef __attribute__((ext_vector_type(2))) uint32_t u32x2;
typedef __attribute__((ext_vector_type(4))) float f32x4;

DEV float bf2f(uint16_t u) { union { uint32_t u; float f; } v; v.u = ((uint32_t)u) << 16; return v.f; }
DEV uint16_t f2bf(float f) {
  union { float f; uint32_t u; } v; v.f = f;
  uint32_t r = v.u + 0x7fffu + ((v.u >> 16) & 1u);
  return (uint16_t)(r >> 16);
}
DEV uint16_t f2bf_hw(float f) { return __builtin_bit_cast(unsigned short, (__bf16)f); }

DEV bf16x8 asbf(u16x8 v) { return __builtin_bit_cast(bf16x8, v); }
DEV f32x4 mfma32(bf16x8 a, bf16x8 b, f32x4 c) {
  return __builtin_amdgcn_mfma_f32_16x16x32_bf16(a, b, c, 0, 0, 0);
}

// async global->LDS, 16B per lane (attn staging).
DEV void gload_lds16(const void* g, void* l) {
  __builtin_amdgcn_global_load_lds(
      (const __attribute__((address_space(1))) uint32_t*)g,
      (__attribute__((address_space(3))) uint32_t*)l, 16, 0, 0);
}

// XOR swizzle: 16B slot s of row r <-> slot s^(r&7). Rows are 64 bf16 = 128B.
DEV int swz(int row, int slot) { return slot ^ (row & 7); }

DEV bf16x8 frag8(const uint16_t* l, int row, int slot) {
  u16x8 v = *(const u16x8*)((const char*)l + row * 128 + (swz(row, slot) << 4));
  return asbf(v);
}

// attn1 block decode tables: 63 blocks per (h,b); qt desc (longest chains first)
__constant__ uint8_t QT_TAB[63] = {
  31,31,31,30,30,30,29,29,29,28,28,28,27,27,27,26,26,26,25,25,25,24,24,24,
  23,23,23,22,22,22,
  21,21,20,20,19,19,18,18,17,17,16,16,15,15,14,14,13,13,12,12,11,11,
  10,9,8,7,6,5,4,3,2,1,0};
__constant__ uint8_t SP_TAB[63] = {
  0,1,2,0,1,2,0,1,2,0,1,2,0,1,2,0,1,2,0,1,2,0,1,2,
  0,1,2,0,1,2,
  0,1,0,1,0,1,0,1,0,1,0,1,0,1,0,1,0,1,0,1,0,1,
  0,0,0,0,0,0,0,0,0,0,0};

// ---------------- dtype probe ----------------
__global__ void probe_k(const uint32_t* __restrict__ mask, uint32_t* __restrict__ flag) {
  flag[0] = (mask[1] & 0xFFFFu) ? 1u : 0u;   // 1 = bf16, 0 = f32
}

// ---------------- ingest convert (f32 path only; no-op when bf16) ----------------
__global__ __launch_bounds__(256) void cvt_k(const void* __restrict__ src,
                                             uint16_t* __restrict__ dst, int n,
                                             const uint32_t* __restrict__ flag) {
  if (flag[0]) return;
  const int stride = gridDim.x * 256 * 8;
  for (int i = (blockIdx.x * 256 + threadIdx.x) * 8; i < n; i += stride) {
    const float* sf = (const float*)src + i;
    u16x8 o;
    for (int j = 0; j < 8; j++) o[j] = f2bf(sf[j]);
    *(u16x8*)(dst + i) = o;
  }
}

// ---------------- generic transpose+convert+scale: in[b][R][C] -> out[b][C][R] ----------------
__global__ __launch_bounds__(256) void transpose_k(const void* __restrict__ in_,
                                                   uint16_t* __restrict__ out, int R, int C,
                                                   float scale,
                                                   const uint32_t* __restrict__ flag) {
  __shared__ uint16_t t[32][33];
  const int isbf = (int)flag[0];
  const int b = blockIdx.z;
  const float* in_f = (const float*)in_ + (size_t)b * R * C;
  const uint16_t* in_u = (const uint16_t*)in_ + (size_t)b * R * C;
  out += (size_t)b * R * C;
  const int c0 = blockIdx.x * 32, r0 = blockIdx.y * 32;
  const int tx = threadIdx.x & 31, ty = threadIdx.x >> 5;
  for (int i = 0; i < 4; i++) {
    int r = ty + i * 8;
    size_t idx = (size_t)(r0 + r) * C + c0 + tx;
    uint16_t v;
    if (isbf) v = (scale == 1.0f) ? in_u[idx] : f2bf(bf2f(in_u[idx]) * scale);
    else      v = f2bf(in_f[idx] * scale);
    t[r][tx] = v;
  }
  __syncthreads();
  for (int i = 0; i < 4; i++) {
    int r = ty + i * 8;
    out[(size_t)(c0 + r) * R + r0 + tx] = t[tx][r];
  }
}

// ---------------- fused QKV weight transpose: Wq/Wk/Wv [16][1024][64] -> Wt[3072][1024] ----------------
__global__ __launch_bounds__(256) void transpose_qkv_k(const void* __restrict__ Wq,
                                                       const void* __restrict__ Wk,
                                                       const void* __restrict__ Wv,
                                                       uint16_t* __restrict__ out,
                                                       const uint32_t* __restrict__ flag) {
  __shared__ uint16_t t[32][33];
  const int isbf = (int)flag[0];
  const int which = blockIdx.z >> 4, hh = blockIdx.z & 15;
  const void* in_ = (which == 0 ? Wq : which == 1 ? Wk : Wv);
  const float scale = (which == 0) ? 0.180336880f : 1.0f;   // 0.125*log2(e)
  const int R = 1024, C = 64;
  const float* in_f = (const float*)in_ + (size_t)hh * R * C;
  const uint16_t* in_u = (const uint16_t*)in_ + (size_t)hh * R * C;
  out += ((size_t)which * 16 + hh) * R * C;
  const int c0 = blockIdx.x * 32, r0 = blockIdx.y * 32;
  const int tx = threadIdx.x & 31, ty = threadIdx.x >> 5;
  for (int i = 0; i < 4; i++) {
    int r = ty + i * 8;
    size_t idx = (size_t)(r0 + r) * C + c0 + tx;
    uint16_t v;
    if (isbf) v = (scale == 1.0f) ? in_u[idx] : f2bf(bf2f(in_u[idx]) * scale);
    else      v = f2bf(in_f[idx] * scale);
    t[r][tx] = v;
  }
  __syncthreads();
  for (int i = 0; i < 4; i++) {
    int r = ty + i * 8;
    out[(size_t)(c0 + r) * R + r0 + tx] = t[tx][r];
  }
}

// ---------------- fused QKV projection: C[4096][3072] = A @ Wt^T (R8 structure) ----------------
__global__ __launch_bounds__(256) void proj_k(
    const uint16_t* __restrict__ Aqk_c, const void* __restrict__ Aqk_r,
    const uint16_t* __restrict__ Av_c, const void* __restrict__ Av_r,
    const uint16_t* __restrict__ Wt,
    uint16_t* __restrict__ Q, uint16_t* __restrict__ K, uint16_t* __restrict__ Vt,
    const uint32_t* __restrict__ flag) {
  __shared__ __attribute__((aligned(16))) uint16_t lA[2][128 * 64];
  __shared__ __attribute__((aligned(16))) uint16_t lB[2][128 * 64];
  const int isbf = (int)flag[0];
  const uint16_t* Aqk = isbf ? (const uint16_t*)Aqk_r : Aqk_c;
  const uint16_t* Av  = isbf ? (const uint16_t*)Av_r  : Av_c;
  const int tid = threadIdx.x, lane = tid & 63, wave = tid >> 6;
  const int g = lane >> 4;
  const int m0 = blockIdx.x * 128, n0 = blockIdx.y * 128;
  const int proj = n0 >> 10;
  const uint16_t* A = (proj == 2 ? Av : Aqk);
  const uint16_t* Bt = Wt + (size_t)n0 * 1024;
  const int wm = wave >> 1, wn = wave & 1;
  f32x4 acc[4][4] = {};
  u16x8 ra[4], rb[4];
  const int row0 = tid >> 3, slot0 = tid & 7;
  auto loadT = [&](int kt) {
    for (int i = 0; i < 4; i++) {
      int row = row0 + i * 32;
      ra[i] = *(const u16x8*)(A + (size_t)(m0 + row) * 1024 + kt + slot0 * 8);
      rb[i] = *(const u16x8*)(Bt + (size_t)row * 1024 + kt + slot0 * 8);
    }
  };
  auto writeT = [&](int buf) {
    for (int i = 0; i < 4; i++) {
      int row = row0 + i * 32;
      *(u16x8*)&lA[buf][(row * 8 + swz(row, slot0)) * 8] = ra[i];
      *(u16x8*)&lB[buf][(row * 8 + swz(row, slot0)) * 8] = rb[i];
    }
  };
  loadT(0);
  writeT(0);
  int cur = 0;
  for (int it = 0; it < 16; it++) {
    const int more = (it < 15);
    if (more) loadT((it + 1) * 64);
    __syncthreads();
    for (int kk = 0; kk < 2; kk++) {
      bf16x8 af[4], bfr[4];
      for (int fm = 0; fm < 4; fm++) af[fm] = frag8(lA[cur], wm * 64 + fm * 16 + (lane & 15), kk * 4 + g);
      for (int fn = 0; fn < 4; fn++) bfr[fn] = frag8(lB[cur], wn * 64 + fn * 16 + (lane & 15), kk * 4 + g);
      for (int fm = 0; fm < 4; fm++)
        for (int fn = 0; fn < 4; fn++)
          acc[fm][fn] = mfma32(af[fm], bfr[fn], acc[fm][fn]);
    }
    if (more) writeT(cur ^ 1);
    cur ^= 1;
  }
  if (proj != 2) {
    uint16_t* outp = (proj == 0 ? Q : K);
    for (int fm = 0; fm < 4; fm++)
      for (int fn = 0; fn < 4; fn++)
        for (int r = 0; r < 4; r++) {
          int row = m0 + wm * 64 + fm * 16 + g * 4 + r;
          int b = row >> 11, s = row & 2047;
          int col = n0 + wn * 64 + fn * 16 + (lane & 15);
          int h = (col >> 6) & 15, e = col & 63;
          outp[(((size_t)(b * 16 + h)) * 2048 + s) * 64 + e] = f2bf(acc[fm][fn][r]);
        }
  } else {
    __syncthreads();
    uint16_t* tv = (uint16_t*)lA;   // 32 KB: 128 cols x 256B
    for (int fm = 0; fm < 4; fm++)
      for (int fn = 0; fn < 4; fn++)
        for (int r = 0; r < 4; r++) {
          int rl = wm * 64 + fm * 16 + g * 4 + r;
          int cl = wn * 64 + fn * 16 + (lane & 15);
          int byte = rl * 2;
          *(uint16_t*)((char*)tv + cl * 256 + ((((byte >> 4)) ^ (cl & 15)) << 4) + (byte & 15)) =
              f2bf(acc[fm][fn][r]);
        }
    __syncthreads();
    const int b = m0 >> 11, s0 = m0 & 2047;
    const int c = tid >> 1, half = tid & 1;
    const int col = n0 + c;
    const int h = (col >> 6) & 15, e = col & 63;
    uint16_t* dst = Vt + (((size_t)(b * 16 + h)) * 64 + e) * 2048 + s0 + half * 64;
    for (int j = 0; j < 8; j++) {
      int rl = half * 64 + j * 8;
      u16x8 v = *(const u16x8*)((const char*)tv + c * 256 + (((rl >> 3) ^ (c & 15)) << 4));
      *(u16x8*)(dst + j * 8) = v;
    }
  }
}

// ---------------- causal flash attention: single-group, CHUNK=11, 3-way, no empties ----------------
// grid (63, 16, 2). (qt, split) from QT_TAB/SP_TAB; tiles [11*split, min(+11, qt+1)).
__global__ __launch_bounds__(256) void attn1_k(const uint16_t* __restrict__ Q,
                                               const uint16_t* __restrict__ K,
                                               const uint16_t* __restrict__ Vt,
                                               uint16_t* __restrict__ Op0,
                                               uint16_t* __restrict__ Op1,
                                               uint16_t* __restrict__ Op2,
                                               float* __restrict__ lbuf) {
  __shared__ __attribute__((aligned(16))) uint16_t lK[2][64 * 64];
  __shared__ __attribute__((aligned(16))) uint16_t lV[2][64 * 64];
  __shared__ __attribute__((aligned(16))) uint16_t lP[4][16 * 64];
  const int tid = threadIdx.x, lane = tid & 63, wave = tid >> 6;
  const int g = lane >> 4, qrow = lane & 15;
  const int bx = blockIdx.x, h = blockIdx.y, b = blockIdx.z;
  const int qt = QT_TAB[bx], split = SP_TAB[bx];
  const int kt0 = split * 11;
  const int lim = qt + 1;
  const int kt1 = (kt0 + 11 < lim) ? kt0 + 11 : lim;
  const size_t bh = (size_t)(b * 16 + h);
  const uint16_t* Qg = Q + bh * 2048 * 64;
  const uint16_t* Kg = K + bh * 2048 * 64;
  const uint16_t* Vg = Vt + bh * 64 * 2048;
  uint16_t* lPw = lP[wave];
  bf16x8 ones;
  for (int j = 0; j < 8; j++) ones[j] = (__bf16)1.0f;
  const int lrow = lane >> 3, sl = lane & 7;
  auto STAGE = [&](int buf, int kt) {
    for (int i = 0; i < 2; i++) {
      int cb = (i * 4 + wave) * 64;
      int row = (cb >> 3) + lrow;
      int so = swz(row, sl) << 3;
      gload_lds16(Kg + (size_t)(kt * 64 + row) * 64 + so, &lK[buf][cb * 8]);
      gload_lds16(Vg + (size_t)row * 2048 + kt * 64 + so, &lV[buf][cb * 8]);
    }
  };
  const int q0 = qt * 64;
  bf16x8 qf[2];
  {
    int row = q0 + wave * 16 + qrow;
    for (int kk = 0; kk < 2; kk++)
      qf[kk] = asbf(*(const u16x8*)(Qg + (size_t)row * 64 + kk * 32 + g * 8));
  }
  f32x4 oacc[4] = {};
  f32x4 acc_l = {};
  STAGE(0, kt0);
  int buf = 0;
  for (int kt = kt0; kt < kt1; kt++) {
    __syncthreads();
    if (kt + 1 < kt1) STAGE(buf ^ 1, kt + 1);
    f32x4 s[4] = {};
    for (int kk = 0; kk < 2; kk++)
      for (int nf = 0; nf < 4; nf++)
        s[nf] = mfma32(frag8(lK[buf], nf * 16 + qrow, kk * 4 + g), qf[kk], s[nf]);
    if (kt == qt) {
      for (int nf = 0; nf < 4; nf++)
        for (int r = 0; r < 4; r++) {
          int kloc = nf * 16 + g * 4 + r;
          if (kloc > wave * 16 + qrow) s[nf][r] = -1e9f;
        }
    }
    for (int nf = 0; nf < 4; nf++) {
      float p0 = __builtin_amdgcn_exp2f(s[nf][0]);
      float p1 = __builtin_amdgcn_exp2f(s[nf][1]);
      float p2 = __builtin_amdgcn_exp2f(s[nf][2]);
      float p3 = __builtin_amdgcn_exp2f(s[nf][3]);
      u32x2 w;
      w[0] = ((uint32_t)f2bf_hw(p1) << 16) | f2bf_hw(p0);
      w[1] = ((uint32_t)f2bf_hw(p3) << 16) | f2bf_hw(p2);
      int slot = 2 * nf + (g >> 1);
      *(u32x2*)((char*)lPw + qrow * 128 + ((slot ^ (qrow & 7)) << 4) + ((g & 1) << 3)) = w;
    }
    for (int kk = 0; kk < 2; kk++) {
      bf16x8 pa = frag8(lPw, qrow, kk * 4 + g);
      acc_l = mfma32(pa, ones, acc_l);
      for (int df = 0; df < 4; df++)
        oacc[df] = mfma32(pa, frag8(lV[buf], df * 16 + qrow, kk * 4 + g), oacc[df]);
    }
    buf ^= 1;
  }
  uint16_t* Op = (split == 0) ? Op0 : (split == 1) ? Op1 : Op2;
  for (int df = 0; df < 4; df++)
    for (int r = 0; r < 4; r++) {
      int srow = q0 + wave * 16 + g * 4 + r;
      int e = df * 16 + qrow;
      Op[((size_t)b * 2048 + srow) * 1024 + h * 64 + e] = f2bf(oacc[df][r]);
    }
  if (qrow == 0) {
    for (int r = 0; r < 4; r++) {
      int srow = q0 + wave * 16 + g * 4 + r;
      lbuf[((size_t)(split * 2 + b) * 16 + h) * 2048 + srow] = acc_l[r];
    }
  }
}

// ---------------- merge (attn1): conditional 1/2/3-way by qt ----------------
__global__ __launch_bounds__(256) void merge3_k(const uint16_t* __restrict__ O0,
                                                const uint16_t* __restrict__ O1,
                                                const uint16_t* __restrict__ O2,
                                                const float* __restrict__ lbuf,
                                                uint16_t* __restrict__ out) {
  int i = (blockIdx.x * 256 + threadIdx.x) * 8;
  int sg = i >> 10;
  int b = sg >> 11, s = sg & 2047;
  int h = (i & 1023) >> 6;
  const int qt = s >> 6;
  const int nch = (qt + 11) / 11;               // ceil((qt+1)/11)
  float l = lbuf[((size_t)b * 16 + h) * 2048 + s];
  u16x8 o0 = *(const u16x8*)(O0 + i);
  float acc[8];
  for (int j = 0; j < 8; j++) acc[j] = bf2f(o0[j]);
  if (nch >= 2) {
    l += lbuf[((size_t)(2 + b) * 16 + h) * 2048 + s];
    u16x8 o1 = *(const u16x8*)(O1 + i);
    for (int j = 0; j < 8; j++) acc[j] += bf2f(o1[j]);
  }
  if (nch >= 3) {
    l += lbuf[((size_t)(4 + b) * 16 + h) * 2048 + s];
    u16x8 o2 = *(const u16x8*)(O2 + i);
    for (int j = 0; j < 8; j++) acc[j] += bf2f(o2[j]);
  }
  float inv = 1.f / l;
  u16x8 o;
  for (int j = 0; j < 8; j++) o[j] = f2bf(acc[j] * inv);
  *(u16x8*)(out + i) = o;
}

// ---------------- non-causal flash attention: dual-group (128 q/block), 4-way split ----------------
__global__ __launch_bounds__(256) void attn2_k(const uint16_t* __restrict__ Q,
                                               const uint16_t* __restrict__ K,
                                               const uint16_t* __restrict__ Vt,
                                               uint16_t* __restrict__ Op0,
                                               uint16_t* __restrict__ Op1,
                                               uint16_t* __restrict__ Op2,
                                               uint16_t* __restrict__ Op3,
                                               float* __restrict__ lbuf) {
  __shared__ __attribute__((aligned(16))) uint16_t lK[2][64 * 64];
  __shared__ __attribute__((aligned(16))) uint16_t lV[2][64 * 64];
  __shared__ __attribute__((aligned(16))) uint16_t lP[8][16 * 64];
  const int tid = threadIdx.x, lane = tid & 63, wave = tid >> 6;
  const int g = lane >> 4, qrow = lane & 15;
  const int bx = blockIdx.x, h = blockIdx.y, b = blockIdx.z;
  const int pair = bx >> 2, split = bx & 3;
  const int kt0 = split * 8, kt1 = kt0 + 8;
  const int q0 = pair * 128;
  const size_t bh = (size_t)(b * 16 + h);
  const uint16_t* Qg = Q + bh * 2048 * 64;
  const uint16_t* Kg = K + bh * 2048 * 64;
  const uint16_t* Vg = Vt + bh * 64 * 2048;
  uint16_t* lP0 = lP[wave * 2];
  uint16_t* lP1 = lP[wave * 2 + 1];
  bf16x8 ones;
  for (int j = 0; j < 8; j++) ones[j] = (__bf16)1.0f;
  const int lrow = lane >> 3, sl = lane & 7;
  auto STAGE = [&](int buf, int kt) {
    for (int i = 0; i < 2; i++) {
      int cb = (i * 4 + wave) * 64;
      int row = (cb >> 3) + lrow;
      int so = swz(row, sl) << 3;
      gload_lds16(Kg + (size_t)(kt * 64 + row) * 64 + so, &lK[buf][cb * 8]);
      gload_lds16(Vg + (size_t)row * 2048 + kt * 64 + so, &lV[buf][cb * 8]);
    }
  };
  bf16x8 qf[2][2];
#pragma unroll
  for (int grp = 0; grp < 2; grp++) {
    int row = q0 + grp * 64 + wave * 16 + qrow;
    for (int kk = 0; kk < 2; kk++)
      qf[grp][kk] = asbf(*(const u16x8*)(Qg + (size_t)row * 64 + kk * 32 + g * 8));
  }
  f32x4 oacc[2][4] = {};
  f32x4 acc_l[2] = {};
  auto storeP = [&](uint16_t* lPw, f32x4 (&s)[4]) {
#pragma unroll
    for (int nf = 0; nf < 4; nf++) {
      float p0 = __builtin_amdgcn_exp2f(s[nf][0]);
      float p1 = __builtin_amdgcn_exp2f(s[nf][1]);
      float p2 = __builtin_amdgcn_exp2f(s[nf][2]);
      float p3 = __builtin_amdgcn_exp2f(s[nf][3]);
      u32x2 w;
      w[0] = ((uint32_t)f2bf_hw(p1) << 16) | f2bf_hw(p0);
      w[1] = ((uint32_t)f2bf_hw(p3) << 16) | f2bf_hw(p2);
      int slot = 2 * nf + (g >> 1);
      *(u32x2*)((char*)lPw + qrow * 128 + ((slot ^ (qrow & 7)) << 4) + ((g & 1) << 3)) = w;
    }
  };
  STAGE(0, kt0);
  int buf = 0;
  for (int kt = kt0; kt < kt1; kt++) {
    __syncthreads();
    if (kt + 1 < kt1) STAGE(buf ^ 1, kt + 1);
    f32x4 s0[4] = {}, s1[4] = {};
#pragma unroll
    for (int kk = 0; kk < 2; kk++)
#pragma unroll
      for (int nf = 0; nf < 4; nf++) {
        bf16x8 kf = frag8(lK[buf], nf * 16 + qrow, kk * 4 + g);
        s0[nf] = mfma32(kf, qf[0][kk], s0[nf]);
        s1[nf] = mfma32(kf, qf[1][kk], s1[nf]);
      }
    storeP(lP0, s0);
    storeP(lP1, s1);
#pragma unroll
    for (int kk = 0; kk < 2; kk++) {
      bf16x8 pa0 = frag8(lP0, qrow, kk * 4 + g);
      bf16x8 pa1 = frag8(lP1, qrow, kk * 4 + g);
      acc_l[0] = mfma32(pa0, ones, acc_l[0]);
      acc_l[1] = mfma32(pa1, ones, acc_l[1]);
#pragma unroll
      for (int df = 0; df < 4; df++) {
        bf16x8 vf = frag8(lV[buf], df * 16 + qrow, kk * 4 + g);
        oacc[0][df] = mfma32(pa0, vf, oacc[0][df]);
        oacc[1][df] = mfma32(pa1, vf, oacc[1][df]);
      }
    }
    buf ^= 1;
  }
  uint16_t* Op = (split == 0) ? Op0 : (split == 1) ? Op1 : (split == 2) ? Op2 : Op3;
#pragma unroll
  for (int grp = 0; grp < 2; grp++)
    for (int df = 0; df < 4; df++)
      for (int r = 0; r < 4; r++) {
        int srow = q0 + grp * 64 + wave * 16 + g * 4 + r;
        int e = df * 16 + qrow;
        Op[((size_t)b * 2048 + srow) * 1024 + h * 64 + e] = f2bf(oacc[grp][df][r]);
      }
  if (qrow == 0) {
#pragma unroll
    for (int grp = 0; grp < 2; grp++)
      for (int r = 0; r < 4; r++) {
        int srow = q0 + grp * 64 + wave * 16 + g * 4 + r;
        lbuf[((size_t)(split * 2 + b) * 16 + h) * 2048 + srow] = acc_l[grp][r];
      }
  }
}

// ---------------- merge (attn2): 4-way ----------------
__global__ __launch_bounds__(256) void merge4_k(const uint16_t* __restrict__ O0,
                                                const uint16_t* __restrict__ O1,
                                                const uint16_t* __restrict__ O2,
                                                const uint16_t* __restrict__ O3,
                                                const float* __restrict__ lbuf,
                                                uint16_t* __restrict__ out) {
  int i = (blockIdx.x * 256 + threadIdx.x) * 8;
  int sg = i >> 10;
  int b = sg >> 11, s = sg & 2047;
  int h = (i & 1023) >> 6;
  float l = 0.f;
  for (int sp = 0; sp < 4; sp++)
    l += lbuf[((size_t)(sp * 2 + b) * 16 + h) * 2048 + s];
  float inv = 1.f / l;
  u16x8 o0 = *(const u16x8*)(O0 + i);
  u16x8 o1 = *(const u16x8*)(O1 + i);
  u16x8 o2 = *(const u16x8*)(O2 + i);
  u16x8 o3 = *(const u16x8*)(O3 + i);
  u16x8 o;
  for (int j = 0; j < 8; j++)
    o[j] = f2bf((bf2f(o0[j]) + bf2f(o1[j]) + bf2f(o2[j]) + bf2f(o3[j])) * inv);
  *(u16x8*)(out + i) = o;
}

// ---------------- FFN GEMM: C[M,N] = A[M,K] @ Bt[N,K]^T (+bias raw, relu), R8 dbuf ----------------
// FINAL=1: C is void*, dtype selected by flag (fused output store).
template <int RELU, int FINAL>
__global__ __launch_bounds__(256) void ff_k(const uint16_t* __restrict__ A,
                                            const uint16_t* __restrict__ Bt,
                                            const void* __restrict__ bias,
                                            void* __restrict__ C, int Kdim, int N,
                                            const uint32_t* __restrict__ flag) {
  __shared__ __attribute__((aligned(16))) uint16_t lA[2][128 * 64];
  __shared__ __attribute__((aligned(16))) uint16_t lB[2][128 * 64];
  const int isbf = (int)flag[0];
  const int tid = threadIdx.x, lane = tid & 63, wave = tid >> 6;
  const int g = lane >> 4;
  const int m0 = blockIdx.x * 128, n0 = blockIdx.y * 128;
  const int wm = wave >> 1, wn = wave & 1;
  f32x4 acc[4][4] = {};
  u16x8 ra[4], rb[4];
  const int row0 = tid >> 3, slot0 = tid & 7;
  auto loadT = [&](int kt) {
    for (int i = 0; i < 4; i++) {
      int row = row0 + i * 32;
      ra[i] = *(const u16x8*)(A + (size_t)(m0 + row) * Kdim + kt + slot0 * 8);
      rb[i] = *(const u16x8*)(Bt + (size_t)(n0 + row) * Kdim + kt + slot0 * 8);
    }
  };
  auto writeT = [&](int buf) {
    for (int i = 0; i < 4; i++) {
      int row = row0 + i * 32;
      *(u16x8*)&lA[buf][(row * 8 + swz(row, slot0)) * 8] = ra[i];
      *(u16x8*)&lB[buf][(row * 8 + swz(row, slot0)) * 8] = rb[i];
    }
  };
  loadT(0);
  writeT(0);
  int cur = 0;
  const int nit = Kdim >> 6;
  for (int it = 0; it < nit; it++) {
    const int more = (it < nit - 1);
    if (more) loadT((it + 1) * 64);
    __syncthreads();
    for (int kk = 0; kk < 2; kk++) {
      bf16x8 af[4], bfr[4];
      for (int fm = 0; fm < 4; fm++) af[fm] = frag8(lA[cur], wm * 64 + fm * 16 + (lane & 15), kk * 4 + g);
      for (int fn = 0; fn < 4; fn++) bfr[fn] = frag8(lB[cur], wn * 64 + fn * 16 + (lane & 15), kk * 4 + g);
      for (int fm = 0; fm < 4; fm++)
        for (int fn = 0; fn < 4; fn++)
          acc[fm][fn] = mfma32(af[fm], bfr[fn], acc[fm][fn]);
    }
    if (more) writeT(cur ^ 1);
    cur ^= 1;
  }
  for (int fm = 0; fm < 4; fm++)
    for (int fn = 0; fn < 4; fn++) {
      int col = n0 + wn * 64 + fn * 16 + (lane & 15);
      float bv = isbf ? bf2f(((const uint16_t*)bias)[col]) : ((const float*)bias)[col];
      for (int r = 0; r < 4; r++) {
        int row = m0 + wm * 64 + fm * 16 + g * 4 + r;
        float v = acc[fm][fn][r] + bv;
        if (RELU) v = fmaxf(v, 0.f);
        size_t idx = (size_t)row * N + col;
        if (!FINAL || isbf) ((uint16_t*)C)[idx] = f2bf(v);
        else                ((float*)C)[idx] = v;
      }
    }
}

extern "C" void kernel_launch(void* const* d_in, const int* in_sizes, int n_in,
                              void* d_out, int out_size, void* d_ws, size_t ws_size,
                              hipStream_t stream) {
  const void* de_x = d_in[0];
  const void* en_x = d_in[1];
  const void* mask = d_in[2];
  const void* Wq = d_in[3];
  const void* Wk = d_in[4];
  const void* Wv = d_in[5];
  const void* W1 = d_in[6];
  const void* b1 = d_in[7];
  const void* W2 = d_in[8];
  const void* b2 = d_in[9];

  uint16_t* ws = (uint16_t*)d_ws;
  const size_t M1 = (size_t)1 << 20;
  uint32_t* flag = (uint32_t*)ws;
  float* lbuf = (float*)(ws + 8192);           // [8][b-folded][16][2048] f32 = 1MB
  uint16_t* Wtq = ws + 1 * M1;                 // [3][16][64][1024] contiguous (Q scaled)
  uint16_t* W1t = ws + 4 * M1;                 // [2048][1024]
  uint16_t* W2t = ws + 6 * M1;                 // [1024][2048]
  uint16_t* de_c = ws + 8 * M1;                // f32 path only
  uint16_t* en_c = ws + 12 * M1;
  uint16_t* Qb  = ws + 16 * M1;                // [B,H,S,64]
  uint16_t* Kb  = ws + 20 * M1;
  uint16_t* Vtb = ws + 24 * M1;                // [B,H,64,S]
  uint16_t* h1  = ws + 28 * M1;
  uint16_t* h2  = ws + 32 * M1;
  uint16_t* ff1 = Qb;                          // reuse
  // attn1 partials: de_c (dead after proj1), h2 (free until ff1), h1 (merge in-place)
  // attn2 partials: de_c, en_c (dead after proj2), h1 (dead after proj2), h2 (merge in-place)

  const int NX = 2 * 2048 * 1024;
  dim3 blk(256);

  probe_k<<<1, 1, 0, stream>>>((const uint32_t*)mask, flag);
  cvt_k<<<2048, blk, 0, stream>>>(de_x, de_c, NX, flag);   // no-op when bf16
  cvt_k<<<2048, blk, 0, stream>>>(en_x, en_c, NX, flag);   // no-op when bf16
  transpose_qkv_k<<<dim3(2, 32, 48), blk, 0, stream>>>(Wq, Wk, Wv, Wtq, flag);
  transpose_k<<<dim3(64, 32, 1), blk, 0, stream>>>(W1, W1t, 1024, 2048, 1.0f, flag);
  transpose_k<<<dim3(32, 64, 1), blk, 0, stream>>>(W2, W2t, 2048, 1024, 1.0f, flag);
  // MHA1: q=k=v=de_x, causal, balanced CHUNK=11 3-way split-K
  proj_k<<<dim3(32, 24), blk, 0, stream>>>(de_c, de_x, de_c, de_x, Wtq, Qb, Kb, Vtb, flag);
  attn1_k<<<dim3(63, 16, 2), blk, 0, stream>>>(Qb, Kb, Vtb, de_c, h2, h1, lbuf);
  merge3_k<<<2048, blk, 0, stream>>>(de_c, h2, h1, lbuf, h1);
  // MHA2: q=k=en_x, v=h1, no mask, dual-group 4-way split-K
  proj_k<<<dim3(32, 24), blk, 0, stream>>>(en_c, en_x, h1, h1, Wtq, Qb, Kb, Vtb, flag);
  attn2_k<<<dim3(64, 16, 2), blk, 0, stream>>>(Qb, Kb, Vtb, de_c, en_c, h1, h2, lbuf);
  merge4_k<<<2048, blk, 0, stream>>>(de_c, en_c, h1, h2, lbuf, h2);
  // FFN (biases read raw, flag-selected); ff2 writes d_out directly
  ff_k<1, 0><<<dim3(32, 16), blk, 0, stream>>>(h2, W1t, b1, ff1, 1024, 2048, flag);
  ff_k<0, 1><<<dim3(32, 8), blk, 0, stream>>>(ff1, W2t, b2, d_out, 2048, 1024, flag);
}

// Round 19
// 253.350 us; speedup vs baseline: 1.1120x; 1.0189x over previous
//
#include <hip/hip_runtime.h>
#include <stdint.h>

// DecoderLayer: B=2, S=2048, DIM=1024, H=16, DH=64, DFF=2048
// Round 19: R18 (best, 258.1us) + launch trim: single cvt kernel for both
// inputs; single flat-grid transpose kernel for QKV + W1 + W2. 12 -> 9
// dispatches. All compute kernels byte-identical to R18.

#define DEV static __device__ __forceinline__

typedef __attribute__((ext_vector_type(8))) __bf16 bf16x8;           // MFMA A/B
typedef __attribute__((ext_vector_type(8))) unsigned short u16x8;
typedef __attribute__((ext_vector_type(2))) uint32_t u32x2;
typedef __attribute__((ext_vector_type(4))) float f32x4;

DEV float bf2f(uint16_t u) { union { uint32_t u; float f; } v; v.u = ((uint32_t)u) << 16; return v.f; }
DEV uint16_t f2bf(float f) {
  union { float f; uint32_t u; } v; v.f = f;
  uint32_t r = v.u + 0x7fffu + ((v.u >> 16) & 1u);
  return (uint16_t)(r >> 16);
}
DEV uint16_t f2bf_hw(float f) { return __builtin_bit_cast(unsigned short, (__bf16)f); }

DEV bf16x8 asbf(u16x8 v) { return __builtin_bit_cast(bf16x8, v); }
DEV f32x4 mfma32(bf16x8 a, bf16x8 b, f32x4 c) {
  return __builtin_amdgcn_mfma_f32_16x16x32_bf16(a, b, c, 0, 0, 0);
}

// async global->LDS, 16B per lane (attn staging).
DEV void gload_lds16(const void* g, void* l) {
  __builtin_amdgcn_global_load_lds(
      (const __attribute__((address_space(1))) uint32_t*)g,
      (__attribute__((address_space(3))) uint32_t*)l, 16, 0, 0);
}

// XOR swizzle: 16B slot s of row r <-> slot s^(r&7). Rows are 64 bf16 = 128B.
DEV int swz(int row, int slot) { return slot ^ (row & 7); }

DEV bf16x8 frag8(const uint16_t* l, int row, int slot) {
  u16x8 v = *(const u16x8*)((const char*)l + row * 128 + (swz(row, slot) << 4));
  return asbf(v);
}

// attn1 block decode tables: 63 blocks per (h,b); qt desc (longest chains first)
__constant__ uint8_t QT_TAB[63] = {
  31,31,31,30,30,30,29,29,29,28,28,28,27,27,27,26,26,26,25,25,25,24,24,24,
  23,23,23,22,22,22,
  21,21,20,20,19,19,18,18,17,17,16,16,15,15,14,14,13,13,12,12,11,11,
  10,9,8,7,6,5,4,3,2,1,0};
__constant__ uint8_t SP_TAB[63] = {
  0,1,2,0,1,2,0,1,2,0,1,2,0,1,2,0,1,2,0,1,2,0,1,2,
  0,1,2,0,1,2,
  0,1,0,1,0,1,0,1,0,1,0,1,0,1,0,1,0,1,0,1,0,1,
  0,0,0,0,0,0,0,0,0,0,0};

// ---------------- dtype probe ----------------
__global__ void probe_k(const uint32_t* __restrict__ mask, uint32_t* __restrict__ flag) {
  flag[0] = (mask[1] & 0xFFFFu) ? 1u : 0u;   // 1 = bf16, 0 = f32
}

// ---------------- ingest convert, both inputs (f32 path only; no-op when bf16) ----------------
__global__ __launch_bounds__(256) void cvt_both_k(const void* __restrict__ src0,
                                                  uint16_t* __restrict__ dst0,
                                                  const void* __restrict__ src1,
                                                  uint16_t* __restrict__ dst1, int n,
                                                  const uint32_t* __restrict__ flag) {
  if (flag[0]) return;
  const int stride = gridDim.x * 256 * 8;
  for (int i = (blockIdx.x * 256 + threadIdx.x) * 8; i < 2 * n; i += stride) {
    const float* sf = (i < n ? (const float*)src0 + i : (const float*)src1 + (i - n));
    uint16_t* d = (i < n ? dst0 + i : dst1 + (i - n));
    u16x8 o;
    for (int j = 0; j < 8; j++) o[j] = f2bf(sf[j]);
    *(u16x8*)d = o;
  }
}

// ---------------- all weight transposes in one launch ----------------
// flat grid 7168: [0,3072) QKV heads -> Wt[3072][1024] (Q scaled by 0.125*log2e);
// [3072,5120) W1 [1024][2048] -> W1t[2048][1024]; [5120,7168) W2 -> W2t.
__global__ __launch_bounds__(256) void transpose_all_k(const void* __restrict__ Wq,
                                                       const void* __restrict__ Wk,
                                                       const void* __restrict__ Wv,
                                                       const void* __restrict__ W1,
                                                       const void* __restrict__ W2,
                                                       uint16_t* __restrict__ Wt,
                                                       uint16_t* __restrict__ W1t,
                                                       uint16_t* __restrict__ W2t,
                                                       const uint32_t* __restrict__ flag) {
  __shared__ uint16_t t[32][33];
  const int isbf = (int)flag[0];
  const int idx = blockIdx.x;
  const void* in_;
  uint16_t* out;
  int R, C, r0, c0;
  float scale = 1.0f;
  if (idx < 3072) {
    int w = idx >> 6, rem = idx & 63;         // w: which*16+h (0..47)
    int which = w >> 4;
    in_ = (which == 0 ? Wq : which == 1 ? Wk : Wv);
    R = 1024; C = 64;
    in_ = (const char*)in_ + (size_t)(w & 15) * R * C * (isbf ? 2 : 4);
    out = Wt + (size_t)w * R * C;
    r0 = (rem >> 1) * 32; c0 = (rem & 1) * 32;
    if (which == 0) scale = 0.180336880f;     // 0.125*log2(e)
  } else if (idx < 5120) {
    int rem = idx - 3072;
    in_ = W1; out = W1t; R = 1024; C = 2048;
    c0 = (rem & 63) * 32; r0 = (rem >> 6) * 32;
  } else {
    int rem = idx - 5120;
    in_ = W2; out = W2t; R = 2048; C = 1024;
    c0 = (rem & 31) * 32; r0 = (rem >> 5) * 32;
  }
  const float* in_f = (const float*)in_;
  const uint16_t* in_u = (const uint16_t*)in_;
  const int tx = threadIdx.x & 31, ty = threadIdx.x >> 5;
  for (int i = 0; i < 4; i++) {
    int r = ty + i * 8;
    size_t id = (size_t)(r0 + r) * C + c0 + tx;
    uint16_t v;
    if (isbf) v = (scale == 1.0f) ? in_u[id] : f2bf(bf2f(in_u[id]) * scale);
    else      v = f2bf(in_f[id] * scale);
    t[r][tx] = v;
  }
  __syncthreads();
  for (int i = 0; i < 4; i++) {
    int r = ty + i * 8;
    out[(size_t)(c0 + r) * R + r0 + tx] = t[tx][r];
  }
}

// ---------------- fused QKV projection: C[4096][3072] = A @ Wt^T (R8 structure) ----------------
__global__ __launch_bounds__(256) void proj_k(
    const uint16_t* __restrict__ Aqk_c, const void* __restrict__ Aqk_r,
    const uint16_t* __restrict__ Av_c, const void* __restrict__ Av_r,
    const uint16_t* __restrict__ Wt,
    uint16_t* __restrict__ Q, uint16_t* __restrict__ K, uint16_t* __restrict__ Vt,
    const uint32_t* __restrict__ flag) {
  __shared__ __attribute__((aligned(16))) uint16_t lA[2][128 * 64];
  __shared__ __attribute__((aligned(16))) uint16_t lB[2][128 * 64];
  const int isbf = (int)flag[0];
  const uint16_t* Aqk = isbf ? (const uint16_t*)Aqk_r : Aqk_c;
  const uint16_t* Av  = isbf ? (const uint16_t*)Av_r  : Av_c;
  const int tid = threadIdx.x, lane = tid & 63, wave = tid >> 6;
  const int g = lane >> 4;
  const int m0 = blockIdx.x * 128, n0 = blockIdx.y * 128;
  const int proj = n0 >> 10;
  const uint16_t* A = (proj == 2 ? Av : Aqk);
  const uint16_t* Bt = Wt + (size_t)n0 * 1024;
  const int wm = wave >> 1, wn = wave & 1;
  f32x4 acc[4][4] = {};
  u16x8 ra[4], rb[4];
  const int row0 = tid >> 3, slot0 = tid & 7;
  auto loadT = [&](int kt) {
    for (int i = 0; i < 4; i++) {
      int row = row0 + i * 32;
      ra[i] = *(const u16x8*)(A + (size_t)(m0 + row) * 1024 + kt + slot0 * 8);
      rb[i] = *(const u16x8*)(Bt + (size_t)row * 1024 + kt + slot0 * 8);
    }
  };
  auto writeT = [&](int buf) {
    for (int i = 0; i < 4; i++) {
      int row = row0 + i * 32;
      *(u16x8*)&lA[buf][(row * 8 + swz(row, slot0)) * 8] = ra[i];
      *(u16x8*)&lB[buf][(row * 8 + swz(row, slot0)) * 8] = rb[i];
    }
  };
  loadT(0);
  writeT(0);
  int cur = 0;
  for (int it = 0; it < 16; it++) {
    const int more = (it < 15);
    if (more) loadT((it + 1) * 64);
    __syncthreads();
    for (int kk = 0; kk < 2; kk++) {
      bf16x8 af[4], bfr[4];
      for (int fm = 0; fm < 4; fm++) af[fm] = frag8(lA[cur], wm * 64 + fm * 16 + (lane & 15), kk * 4 + g);
      for (int fn = 0; fn < 4; fn++) bfr[fn] = frag8(lB[cur], wn * 64 + fn * 16 + (lane & 15), kk * 4 + g);
      for (int fm = 0; fm < 4; fm++)
        for (int fn = 0; fn < 4; fn++)
          acc[fm][fn] = mfma32(af[fm], bfr[fn], acc[fm][fn]);
    }
    if (more) writeT(cur ^ 1);
    cur ^= 1;
  }
  if (proj != 2) {
    uint16_t* outp = (proj == 0 ? Q : K);
    for (int fm = 0; fm < 4; fm++)
      for (int fn = 0; fn < 4; fn++)
        for (int r = 0; r < 4; r++) {
          int row = m0 + wm * 64 + fm * 16 + g * 4 + r;
          int b = row >> 11, s = row & 2047;
          int col = n0 + wn * 64 + fn * 16 + (lane & 15);
          int h = (col >> 6) & 15, e = col & 63;
          outp[(((size_t)(b * 16 + h)) * 2048 + s) * 64 + e] = f2bf(acc[fm][fn][r]);
        }
  } else {
    __syncthreads();
    uint16_t* tv = (uint16_t*)lA;   // 32 KB: 128 cols x 256B
    for (int fm = 0; fm < 4; fm++)
      for (int fn = 0; fn < 4; fn++)
        for (int r = 0; r < 4; r++) {
          int rl = wm * 64 + fm * 16 + g * 4 + r;
          int cl = wn * 64 + fn * 16 + (lane & 15);
          int byte = rl * 2;
          *(uint16_t*)((char*)tv + cl * 256 + ((((byte >> 4)) ^ (cl & 15)) << 4) + (byte & 15)) =
              f2bf(acc[fm][fn][r]);
        }
    __syncthreads();
    const int b = m0 >> 11, s0 = m0 & 2047;
    const int c = tid >> 1, half = tid & 1;
    const int col = n0 + c;
    const int h = (col >> 6) & 15, e = col & 63;
    uint16_t* dst = Vt + (((size_t)(b * 16 + h)) * 64 + e) * 2048 + s0 + half * 64;
    for (int j = 0; j < 8; j++) {
      int rl = half * 64 + j * 8;
      u16x8 v = *(const u16x8*)((const char*)tv + c * 256 + (((rl >> 3) ^ (c & 15)) << 4));
      *(u16x8*)(dst + j * 8) = v;
    }
  }
}

// ---------------- causal flash attention: single-group, CHUNK=11, 3-way, no empties ----------------
// grid (63, 16, 2). (qt, split) from QT_TAB/SP_TAB; tiles [11*split, min(+11, qt+1)).
__global__ __launch_bounds__(256) void attn1_k(const uint16_t* __restrict__ Q,
                                               const uint16_t* __restrict__ K,
                                               const uint16_t* __restrict__ Vt,
                                               uint16_t* __restrict__ Op0,
                                               uint16_t* __restrict__ Op1,
                                               uint16_t* __restrict__ Op2,
                                               float* __restrict__ lbuf) {
  __shared__ __attribute__((aligned(16))) uint16_t lK[2][64 * 64];
  __shared__ __attribute__((aligned(16))) uint16_t lV[2][64 * 64];
  __shared__ __attribute__((aligned(16))) uint16_t lP[4][16 * 64];
  const int tid = threadIdx.x, lane = tid & 63, wave = tid >> 6;
  const int g = lane >> 4, qrow = lane & 15;
  const int bx = blockIdx.x, h = blockIdx.y, b = blockIdx.z;
  const int qt = QT_TAB[bx], split = SP_TAB[bx];
  const int kt0 = split * 11;
  const int lim = qt + 1;
  const int kt1 = (kt0 + 11 < lim) ? kt0 + 11 : lim;
  const size_t bh = (size_t)(b * 16 + h);
  const uint16_t* Qg = Q + bh * 2048 * 64;
  const uint16_t* Kg = K + bh * 2048 * 64;
  const uint16_t* Vg = Vt + bh * 64 * 2048;
  uint16_t* lPw = lP[wave];
  bf16x8 ones;
  for (int j = 0; j < 8; j++) ones[j] = (__bf16)1.0f;
  const int lrow = lane >> 3, sl = lane & 7;
  auto STAGE = [&](int buf, int kt) {
    for (int i = 0; i < 2; i++) {
      int cb = (i * 4 + wave) * 64;
      int row = (cb >> 3) + lrow;
      int so = swz(row, sl) << 3;
      gload_lds16(Kg + (size_t)(kt * 64 + row) * 64 + so, &lK[buf][cb * 8]);
      gload_lds16(Vg + (size_t)row * 2048 + kt * 64 + so, &lV[buf][cb * 8]);
    }
  };
  const int q0 = qt * 64;
  bf16x8 qf[2];
  {
    int row = q0 + wave * 16 + qrow;
    for (int kk = 0; kk < 2; kk++)
      qf[kk] = asbf(*(const u16x8*)(Qg + (size_t)row * 64 + kk * 32 + g * 8));
  }
  f32x4 oacc[4] = {};
  f32x4 acc_l = {};
  STAGE(0, kt0);
  int buf = 0;
  for (int kt = kt0; kt < kt1; kt++) {
    __syncthreads();
    if (kt + 1 < kt1) STAGE(buf ^ 1, kt + 1);
    f32x4 s[4] = {};
    for (int kk = 0; kk < 2; kk++)
      for (int nf = 0; nf < 4; nf++)
        s[nf] = mfma32(frag8(lK[buf], nf * 16 + qrow, kk * 4 + g), qf[kk], s[nf]);
    if (kt == qt) {
      for (int nf = 0; nf < 4; nf++)
        for (int r = 0; r < 4; r++) {
          int kloc = nf * 16 + g * 4 + r;
          if (kloc > wave * 16 + qrow) s[nf][r] = -1e9f;
        }
    }
    for (int nf = 0; nf < 4; nf++) {
      float p0 = __builtin_amdgcn_exp2f(s[nf][0]);
      float p1 = __builtin_amdgcn_exp2f(s[nf][1]);
      float p2 = __builtin_amdgcn_exp2f(s[nf][2]);
      float p3 = __builtin_amdgcn_exp2f(s[nf][3]);
      u32x2 w;
      w[0] = ((uint32_t)f2bf_hw(p1) << 16) | f2bf_hw(p0);
      w[1] = ((uint32_t)f2bf_hw(p3) << 16) | f2bf_hw(p2);
      int slot = 2 * nf + (g >> 1);
      *(u32x2*)((char*)lPw + qrow * 128 + ((slot ^ (qrow & 7)) << 4) + ((g & 1) << 3)) = w;
    }
    for (int kk = 0; kk < 2; kk++) {
      bf16x8 pa = frag8(lPw, qrow, kk * 4 + g);
      acc_l = mfma32(pa, ones, acc_l);
      for (int df = 0; df < 4; df++)
        oacc[df] = mfma32(pa, frag8(lV[buf], df * 16 + qrow, kk * 4 + g), oacc[df]);
    }
    buf ^= 1;
  }
  uint16_t* Op = (split == 0) ? Op0 : (split == 1) ? Op1 : Op2;
  for (int df = 0; df < 4; df++)
    for (int r = 0; r < 4; r++) {
      int srow = q0 + wave * 16 + g * 4 + r;
      int e = df * 16 + qrow;
      Op[((size_t)b * 2048 + srow) * 1024 + h * 64 + e] = f2bf(oacc[df][r]);
    }
  if (qrow == 0) {
    for (int r = 0; r < 4; r++) {
      int srow = q0 + wave * 16 + g * 4 + r;
      lbuf[((size_t)(split * 2 + b) * 16 + h) * 2048 + srow] = acc_l[r];
    }
  }
}

// ---------------- merge (attn1): conditional 1/2/3-way by qt ----------------
__global__ __launch_bounds__(256) void merge3_k(const uint16_t* __restrict__ O0,
                                                const uint16_t* __restrict__ O1,
                                                const uint16_t* __restrict__ O2,
                                                const float* __restrict__ lbuf,
                                                uint16_t* __restrict__ out) {
  int i = (blockIdx.x * 256 + threadIdx.x) * 8;
  int sg = i >> 10;
  int b = sg >> 11, s = sg & 2047;
  int h = (i & 1023) >> 6;
  const int qt = s >> 6;
  const int nch = (qt + 11) / 11;               // ceil((qt+1)/11)
  float l = lbuf[((size_t)b * 16 + h) * 2048 + s];
  u16x8 o0 = *(const u16x8*)(O0 + i);
  float acc[8];
  for (int j = 0; j < 8; j++) acc[j] = bf2f(o0[j]);
  if (nch >= 2) {
    l += lbuf[((size_t)(2 + b) * 16 + h) * 2048 + s];
    u16x8 o1 = *(const u16x8*)(O1 + i);
    for (int j = 0; j < 8; j++) acc[j] += bf2f(o1[j]);
  }
  if (nch >= 3) {
    l += lbuf[((size_t)(4 + b) * 16 + h) * 2048 + s];
    u16x8 o2 = *(const u16x8*)(O2 + i);
    for (int j = 0; j < 8; j++) acc[j] += bf2f(o2[j]);
  }
  float inv = 1.f / l;
  u16x8 o;
  for (int j = 0; j < 8; j++) o[j] = f2bf(acc[j] * inv);
  *(u16x8*)(out + i) = o;
}

// ---------------- non-causal flash attention: dual-group (128 q/block), 4-way split ----------------
__global__ __launch_bounds__(256) void attn2_k(const uint16_t* __restrict__ Q,
                                               const uint16_t* __restrict__ K,
                                               const uint16_t* __restrict__ Vt,
                                               uint16_t* __restrict__ Op0,
                                               uint16_t* __restrict__ Op1,
                                               uint16_t* __restrict__ Op2,
                                               uint16_t* __restrict__ Op3,
                                               float* __restrict__ lbuf) {
  __shared__ __attribute__((aligned(16))) uint16_t lK[2][64 * 64];
  __shared__ __attribute__((aligned(16))) uint16_t lV[2][64 * 64];
  __shared__ __attribute__((aligned(16))) uint16_t lP[8][16 * 64];
  const int tid = threadIdx.x, lane = tid & 63, wave = tid >> 6;
  const int g = lane >> 4, qrow = lane & 15;
  const int bx = blockIdx.x, h = blockIdx.y, b = blockIdx.z;
  const int pair = bx >> 2, split = bx & 3;
  const int kt0 = split * 8, kt1 = kt0 + 8;
  const int q0 = pair * 128;
  const size_t bh = (size_t)(b * 16 + h);
  const uint16_t* Qg = Q + bh * 2048 * 64;
  const uint16_t* Kg = K + bh * 2048 * 64;
  const uint16_t* Vg = Vt + bh * 64 * 2048;
  uint16_t* lP0 = lP[wave * 2];
  uint16_t* lP1 = lP[wave * 2 + 1];
  bf16x8 ones;
  for (int j = 0; j < 8; j++) ones[j] = (__bf16)1.0f;
  const int lrow = lane >> 3, sl = lane & 7;
  auto STAGE = [&](int buf, int kt) {
    for (int i = 0; i < 2; i++) {
      int cb = (i * 4 + wave) * 64;
      int row = (cb >> 3) + lrow;
      int so = swz(row, sl) << 3;
      gload_lds16(Kg + (size_t)(kt * 64 + row) * 64 + so, &lK[buf][cb * 8]);
      gload_lds16(Vg + (size_t)row * 2048 + kt * 64 + so, &lV[buf][cb * 8]);
    }
  };
  bf16x8 qf[2][2];
#pragma unroll
  for (int grp = 0; grp < 2; grp++) {
    int row = q0 + grp * 64 + wave * 16 + qrow;
    for (int kk = 0; kk < 2; kk++)
      qf[grp][kk] = asbf(*(const u16x8*)(Qg + (size_t)row * 64 + kk * 32 + g * 8));
  }
  f32x4 oacc[2][4] = {};
  f32x4 acc_l[2] = {};
  auto storeP = [&](uint16_t* lPw, f32x4 (&s)[4]) {
#pragma unroll
    for (int nf = 0; nf < 4; nf++) {
      float p0 = __builtin_amdgcn_exp2f(s[nf][0]);
      float p1 = __builtin_amdgcn_exp2f(s[nf][1]);
      float p2 = __builtin_amdgcn_exp2f(s[nf][2]);
      float p3 = __builtin_amdgcn_exp2f(s[nf][3]);
      u32x2 w;
      w[0] = ((uint32_t)f2bf_hw(p1) << 16) | f2bf_hw(p0);
      w[1] = ((uint32_t)f2bf_hw(p3) << 16) | f2bf_hw(p2);
      int slot = 2 * nf + (g >> 1);
      *(u32x2*)((char*)lPw + qrow * 128 + ((slot ^ (qrow & 7)) << 4) + ((g & 1) << 3)) = w;
    }
  };
  STAGE(0, kt0);
  int buf = 0;
  for (int kt = kt0; kt < kt1; kt++) {
    __syncthreads();
    if (kt + 1 < kt1) STAGE(buf ^ 1, kt + 1);
    f32x4 s0[4] = {}, s1[4] = {};
#pragma unroll
    for (int kk = 0; kk < 2; kk++)
#pragma unroll
      for (int nf = 0; nf < 4; nf++) {
        bf16x8 kf = frag8(lK[buf], nf * 16 + qrow, kk * 4 + g);
        s0[nf] = mfma32(kf, qf[0][kk], s0[nf]);
        s1[nf] = mfma32(kf, qf[1][kk], s1[nf]);
      }
    storeP(lP0, s0);
    storeP(lP1, s1);
#pragma unroll
    for (int kk = 0; kk < 2; kk++) {
      bf16x8 pa0 = frag8(lP0, qrow, kk * 4 + g);
      bf16x8 pa1 = frag8(lP1, qrow, kk * 4 + g);
      acc_l[0] = mfma32(pa0, ones, acc_l[0]);
      acc_l[1] = mfma32(pa1, ones, acc_l[1]);
#pragma unroll
      for (int df = 0; df < 4; df++) {
        bf16x8 vf = frag8(lV[buf], df * 16 + qrow, kk * 4 + g);
        oacc[0][df] = mfma32(pa0, vf, oacc[0][df]);
        oacc[1][df] = mfma32(pa1, vf, oacc[1][df]);
      }
    }
    buf ^= 1;
  }
  uint16_t* Op = (split == 0) ? Op0 : (split == 1) ? Op1 : (split == 2) ? Op2 : Op3;
#pragma unroll
  for (int grp = 0; grp < 2; grp++)
    for (int df = 0; df < 4; df++)
      for (int r = 0; r < 4; r++) {
        int srow = q0 + grp * 64 + wave * 16 + g * 4 + r;
        int e = df * 16 + qrow;
        Op[((size_t)b * 2048 + srow) * 1024 + h * 64 + e] = f2bf(oacc[grp][df][r]);
      }
  if (qrow == 0) {
#pragma unroll
    for (int grp = 0; grp < 2; grp++)
      for (int r = 0; r < 4; r++) {
        int srow = q0 + grp * 64 + wave * 16 + g * 4 + r;
        lbuf[((size_t)(split * 2 + b) * 16 + h) * 2048 + srow] = acc_l[grp][r];
      }
  }
}

// ---------------- merge (attn2): 4-way ----------------
__global__ __launch_bounds__(256) void merge4_k(const uint16_t* __restrict__ O0,
                                                const uint16_t* __restrict__ O1,
                                                const uint16_t* __restrict__ O2,
                                                const uint16_t* __restrict__ O3,
                                                const float* __restrict__ lbuf,
                                                uint16_t* __restrict__ out) {
  int i = (blockIdx.x * 256 + threadIdx.x) * 8;
  int sg = i >> 10;
  int b = sg >> 11, s = sg & 2047;
  int h = (i & 1023) >> 6;
  float l = 0.f;
  for (int sp = 0; sp < 4; sp++)
    l += lbuf[((size_t)(sp * 2 + b) * 16 + h) * 2048 + s];
  float inv = 1.f / l;
  u16x8 o0 = *(const u16x8*)(O0 + i);
  u16x8 o1 = *(const u16x8*)(O1 + i);
  u16x8 o2 = *(const u16x8*)(O2 + i);
  u16x8 o3 = *(const u16x8*)(O3 + i);
  u16x8 o;
  for (int j = 0; j < 8; j++)
    o[j] = f2bf((bf2f(o0[j]) + bf2f(o1[j]) + bf2f(o2[j]) + bf2f(o3[j])) * inv);
  *(u16x8*)(out + i) = o;
}

// ---------------- FFN GEMM: C[M,N] = A[M,K] @ Bt[N,K]^T (+bias raw, relu), R8 dbuf ----------------
// FINAL=1: C is void*, dtype selected by flag (fused output store).
template <int RELU, int FINAL>
__global__ __launch_bounds__(256) void ff_k(const uint16_t* __restrict__ A,
                                            const uint16_t* __restrict__ Bt,
                                            const void* __restrict__ bias,
                                            void* __restrict__ C, int Kdim, int N,
                                            const uint32_t* __restrict__ flag) {
  __shared__ __attribute__((aligned(16))) uint16_t lA[2][128 * 64];
  __shared__ __attribute__((aligned(16))) uint16_t lB[2][128 * 64];
  const int isbf = (int)flag[0];
  const int tid = threadIdx.x, lane = tid & 63, wave = tid >> 6;
  const int g = lane >> 4;
  const int m0 = blockIdx.x * 128, n0 = blockIdx.y * 128;
  const int wm = wave >> 1, wn = wave & 1;
  f32x4 acc[4][4] = {};
  u16x8 ra[4], rb[4];
  const int row0 = tid >> 3, slot0 = tid & 7;
  auto loadT = [&](int kt) {
    for (int i = 0; i < 4; i++) {
      int row = row0 + i * 32;
      ra[i] = *(const u16x8*)(A + (size_t)(m0 + row) * Kdim + kt + slot0 * 8);
      rb[i] = *(const u16x8*)(Bt + (size_t)(n0 + row) * Kdim + kt + slot0 * 8);
    }
  };
  auto writeT = [&](int buf) {
    for (int i = 0; i < 4; i++) {
      int row = row0 + i * 32;
      *(u16x8*)&lA[buf][(row * 8 + swz(row, slot0)) * 8] = ra[i];
      *(u16x8*)&lB[buf][(row * 8 + swz(row, slot0)) * 8] = rb[i];
    }
  };
  loadT(0);
  writeT(0);
  int cur = 0;
  const int nit = Kdim >> 6;
  for (int it = 0; it < nit; it++) {
    const int more = (it < nit - 1);
    if (more) loadT((it + 1) * 64);
    __syncthreads();
    for (int kk = 0; kk < 2; kk++) {
      bf16x8 af[4], bfr[4];
      for (int fm = 0; fm < 4; fm++) af[fm] = frag8(lA[cur], wm * 64 + fm * 16 + (lane & 15), kk * 4 + g);
      for (int fn = 0; fn < 4; fn++) bfr[fn] = frag8(lB[cur], wn * 64 + fn * 16 + (lane & 15), kk * 4 + g);
      for (int fm = 0; fm < 4; fm++)
        for (int fn = 0; fn < 4; fn++)
          acc[fm][fn] = mfma32(af[fm], bfr[fn], acc[fm][fn]);
    }
    if (more) writeT(cur ^ 1);
    cur ^= 1;
  }
  for (int fm = 0; fm < 4; fm++)
    for (int fn = 0; fn < 4; fn++) {
      int col = n0 + wn * 64 + fn * 16 + (lane & 15);
      float bv = isbf ? bf2f(((const uint16_t*)bias)[col]) : ((const float*)bias)[col];
      for (int r = 0; r < 4; r++) {
        int row = m0 + wm * 64 + fm * 16 + g * 4 + r;
        float v = acc[fm][fn][r] + bv;
        if (RELU) v = fmaxf(v, 0.f);
        size_t idx = (size_t)row * N + col;
        if (!FINAL || isbf) ((uint16_t*)C)[idx] = f2bf(v);
        else                ((float*)C)[idx] = v;
      }
    }
}

extern "C" void kernel_launch(void* const* d_in, const int* in_sizes, int n_in,
                              void* d_out, int out_size, void* d_ws, size_t ws_size,
                              hipStream_t stream) {
  const void* de_x = d_in[0];
  const void* en_x = d_in[1];
  const void* mask = d_in[2];
  const void* Wq = d_in[3];
  const void* Wk = d_in[4];
  const void* Wv = d_in[5];
  const void* W1 = d_in[6];
  const void* b1 = d_in[7];
  const void* W2 = d_in[8];
  const void* b2 = d_in[9];

  uint16_t* ws = (uint16_t*)d_ws;
  const size_t M1 = (size_t)1 << 20;
  uint32_t* flag = (uint32_t*)ws;
  float* lbuf = (float*)(ws + 8192);           // [8][b-folded][16][2048] f32 = 1MB
  uint16_t* Wtq = ws + 1 * M1;                 // [3][16][64][1024] contiguous (Q scaled)
  uint16_t* W1t = ws + 4 * M1;                 // [2048][1024]
  uint16_t* W2t = ws + 6 * M1;                 // [1024][2048]
  uint16_t* de_c = ws + 8 * M1;                // f32 path only
  uint16_t* en_c = ws + 12 * M1;
  uint16_t* Qb  = ws + 16 * M1;                // [B,H,S,64]
  uint16_t* Kb  = ws + 20 * M1;
  uint16_t* Vtb = ws + 24 * M1;                // [B,H,64,S]
  uint16_t* h1  = ws + 28 * M1;
  uint16_t* h2  = ws + 32 * M1;
  uint16_t* ff1 = Qb;                          // reuse
  // attn1 partials: de_c (dead after proj1), h2 (free until ff1), h1 (merge in-place)
  // attn2 partials: de_c, en_c (dead after proj2), h1 (dead after proj2), h2 (merge in-place)

  const int NX = 2 * 2048 * 1024;
  dim3 blk(256);

  probe_k<<<1, 1, 0, stream>>>((const uint32_t*)mask, flag);
  cvt_both_k<<<2048, blk, 0, stream>>>(de_x, de_c, en_x, en_c, NX, flag); // no-op when bf16
  transpose_all_k<<<7168, blk, 0, stream>>>(Wq, Wk, Wv, W1, W2, Wtq, W1t, W2t, flag);
  // MHA1: q=k=v=de_x, causal, balanced CHUNK=11 3-way split-K
  proj_k<<<dim3(32, 24), blk, 0, stream>>>(de_c, de_x, de_c, de_x, Wtq, Qb, Kb, Vtb, flag);
  attn1_k<<<dim3(63, 16, 2), blk, 0, stream>>>(Qb, Kb, Vtb, de_c, h2, h1, lbuf);
  merge3_k<<<2048, blk, 0, stream>>>(de_c, h2, h1, lbuf, h1);
  // MHA2: q=k=en_x, v=h1, no mask, dual-group 4-way split-K
  proj_k<<<dim3(32, 24), blk, 0, stream>>>(en_c, en_x, h1, h1, Wtq, Qb, Kb, Vtb, flag);
  attn2_k<<<dim3(64, 16, 2), blk, 0, stream>>>(Qb, Kb, Vtb, de_c, en_c, h1, h2, lbuf);
  merge4_k<<<2048, blk, 0, stream>>>(de_c, en_c, h1, h2, lbuf, h2);
  // FFN (biases read raw, flag-selected); ff2 writes d_out directly
  ff_k<1, 0><<<dim3(32, 16), blk, 0, stream>>>(h2, W1t, b1, ff1, 1024, 2048, flag);
  ff_k<0, 1><<<dim3(32, 8), blk, 0, stream>>>(ff1, W2t, b2, d_out, 2048, 1024, flag);
}

// Round 20
// 251.167 us; speedup vs baseline: 1.1217x; 1.0087x over previous
//
#include <hip/hip_runtime.h>
#include <stdint.h>

// DecoderLayer: B=2, S=2048, DIM=1024, H=16, DH=64, DFF=2048
// Round 20: R19 (best, 253.3us) + ff2 re-tiled to BM=64 x BN=128 (ff64_k):
// grid 256 -> 512 blocks (1 -> 2 blocks/CU), LDS 48KB. Everything else
// byte-identical to R19.

#define DEV static __device__ __forceinline__

typedef __attribute__((ext_vector_type(8))) __bf16 bf16x8;           // MFMA A/B
typedef __attribute__((ext_vector_type(8))) unsigned short u16x8;
typedef __attribute__((ext_vector_type(2))) uint32_t u32x2;
typedef __attribute__((ext_vector_type(4))) float f32x4;

DEV float bf2f(uint16_t u) { union { uint32_t u; float f; } v; v.u = ((uint32_t)u) << 16; return v.f; }
DEV uint16_t f2bf(float f) {
  union { float f; uint32_t u; } v; v.f = f;
  uint32_t r = v.u + 0x7fffu + ((v.u >> 16) & 1u);
  return (uint16_t)(r >> 16);
}
DEV uint16_t f2bf_hw(float f) { return __builtin_bit_cast(unsigned short, (__bf16)f); }

DEV bf16x8 asbf(u16x8 v) { return __builtin_bit_cast(bf16x8, v); }
DEV f32x4 mfma32(bf16x8 a, bf16x8 b, f32x4 c) {
  return __builtin_amdgcn_mfma_f32_16x16x32_bf16(a, b, c, 0, 0, 0);
}

// async global->LDS, 16B per lane (attn staging).
DEV void gload_lds16(const void* g, void* l) {
  __builtin_amdgcn_global_load_lds(
      (const __attribute__((address_space(1))) uint32_t*)g,
      (__attribute__((address_space(3))) uint32_t*)l, 16, 0, 0);
}

// XOR swizzle: 16B slot s of row r <-> slot s^(r&7). Rows are 64 bf16 = 128B.
DEV int swz(int row, int slot) { return slot ^ (row & 7); }

DEV bf16x8 frag8(const uint16_t* l, int row, int slot) {
  u16x8 v = *(const u16x8*)((const char*)l + row * 128 + (swz(row, slot) << 4));
  return asbf(v);
}

// attn1 block decode tables: 63 blocks per (h,b); qt desc (longest chains first)
__constant__ uint8_t QT_TAB[63] = {
  31,31,31,30,30,30,29,29,29,28,28,28,27,27,27,26,26,26,25,25,25,24,24,24,
  23,23,23,22,22,22,
  21,21,20,20,19,19,18,18,17,17,16,16,15,15,14,14,13,13,12,12,11,11,
  10,9,8,7,6,5,4,3,2,1,0};
__constant__ uint8_t SP_TAB[63] = {
  0,1,2,0,1,2,0,1,2,0,1,2,0,1,2,0,1,2,0,1,2,0,1,2,
  0,1,2,0,1,2,
  0,1,0,1,0,1,0,1,0,1,0,1,0,1,0,1,0,1,0,1,0,1,
  0,0,0,0,0,0,0,0,0,0,0};

// ---------------- dtype probe ----------------
__global__ void probe_k(const uint32_t* __restrict__ mask, uint32_t* __restrict__ flag) {
  flag[0] = (mask[1] & 0xFFFFu) ? 1u : 0u;   // 1 = bf16, 0 = f32
}

// ---------------- ingest convert, both inputs (f32 path only; no-op when bf16) ----------------
__global__ __launch_bounds__(256) void cvt_both_k(const void* __restrict__ src0,
                                                  uint16_t* __restrict__ dst0,
                                                  const void* __restrict__ src1,
                                                  uint16_t* __restrict__ dst1, int n,
                                                  const uint32_t* __restrict__ flag) {
  if (flag[0]) return;
  const int stride = gridDim.x * 256 * 8;
  for (int i = (blockIdx.x * 256 + threadIdx.x) * 8; i < 2 * n; i += stride) {
    const float* sf = (i < n ? (const float*)src0 + i : (const float*)src1 + (i - n));
    uint16_t* d = (i < n ? dst0 + i : dst1 + (i - n));
    u16x8 o;
    for (int j = 0; j < 8; j++) o[j] = f2bf(sf[j]);
    *(u16x8*)d = o;
  }
}

// ---------------- all weight transposes in one launch ----------------
__global__ __launch_bounds__(256) void transpose_all_k(const void* __restrict__ Wq,
                                                       const void* __restrict__ Wk,
                                                       const void* __restrict__ Wv,
                                                       const void* __restrict__ W1,
                                                       const void* __restrict__ W2,
                                                       uint16_t* __restrict__ Wt,
                                                       uint16_t* __restrict__ W1t,
                                                       uint16_t* __restrict__ W2t,
                                                       const uint32_t* __restrict__ flag) {
  __shared__ uint16_t t[32][33];
  const int isbf = (int)flag[0];
  const int idx = blockIdx.x;
  const void* in_;
  uint16_t* out;
  int R, C, r0, c0;
  float scale = 1.0f;
  if (idx < 3072) {
    int w = idx >> 6, rem = idx & 63;         // w: which*16+h (0..47)
    int which = w >> 4;
    in_ = (which == 0 ? Wq : which == 1 ? Wk : Wv);
    R = 1024; C = 64;
    in_ = (const char*)in_ + (size_t)(w & 15) * R * C * (isbf ? 2 : 4);
    out = Wt + (size_t)w * R * C;
    r0 = (rem >> 1) * 32; c0 = (rem & 1) * 32;
    if (which == 0) scale = 0.180336880f;     // 0.125*log2(e)
  } else if (idx < 5120) {
    int rem = idx - 3072;
    in_ = W1; out = W1t; R = 1024; C = 2048;
    c0 = (rem & 63) * 32; r0 = (rem >> 6) * 32;
  } else {
    int rem = idx - 5120;
    in_ = W2; out = W2t; R = 2048; C = 1024;
    c0 = (rem & 31) * 32; r0 = (rem >> 5) * 32;
  }
  const float* in_f = (const float*)in_;
  const uint16_t* in_u = (const uint16_t*)in_;
  const int tx = threadIdx.x & 31, ty = threadIdx.x >> 5;
  for (int i = 0; i < 4; i++) {
    int r = ty + i * 8;
    size_t id = (size_t)(r0 + r) * C + c0 + tx;
    uint16_t v;
    if (isbf) v = (scale == 1.0f) ? in_u[id] : f2bf(bf2f(in_u[id]) * scale);
    else      v = f2bf(in_f[id] * scale);
    t[r][tx] = v;
  }
  __syncthreads();
  for (int i = 0; i < 4; i++) {
    int r = ty + i * 8;
    out[(size_t)(c0 + r) * R + r0 + tx] = t[tx][r];
  }
}

// ---------------- fused QKV projection: C[4096][3072] = A @ Wt^T (R8 structure) ----------------
__global__ __launch_bounds__(256) void proj_k(
    const uint16_t* __restrict__ Aqk_c, const void* __restrict__ Aqk_r,
    const uint16_t* __restrict__ Av_c, const void* __restrict__ Av_r,
    const uint16_t* __restrict__ Wt,
    uint16_t* __restrict__ Q, uint16_t* __restrict__ K, uint16_t* __restrict__ Vt,
    const uint32_t* __restrict__ flag) {
  __shared__ __attribute__((aligned(16))) uint16_t lA[2][128 * 64];
  __shared__ __attribute__((aligned(16))) uint16_t lB[2][128 * 64];
  const int isbf = (int)flag[0];
  const uint16_t* Aqk = isbf ? (const uint16_t*)Aqk_r : Aqk_c;
  const uint16_t* Av  = isbf ? (const uint16_t*)Av_r  : Av_c;
  const int tid = threadIdx.x, lane = tid & 63, wave = tid >> 6;
  const int g = lane >> 4;
  const int m0 = blockIdx.x * 128, n0 = blockIdx.y * 128;
  const int proj = n0 >> 10;
  const uint16_t* A = (proj == 2 ? Av : Aqk);
  const uint16_t* Bt = Wt + (size_t)n0 * 1024;
  const int wm = wave >> 1, wn = wave & 1;
  f32x4 acc[4][4] = {};
  u16x8 ra[4], rb[4];
  const int row0 = tid >> 3, slot0 = tid & 7;
  auto loadT = [&](int kt) {
    for (int i = 0; i < 4; i++) {
      int row = row0 + i * 32;
      ra[i] = *(const u16x8*)(A + (size_t)(m0 + row) * 1024 + kt + slot0 * 8);
      rb[i] = *(const u16x8*)(Bt + (size_t)row * 1024 + kt + slot0 * 8);
    }
  };
  auto writeT = [&](int buf) {
    for (int i = 0; i < 4; i++) {
      int row = row0 + i * 32;
      *(u16x8*)&lA[buf][(row * 8 + swz(row, slot0)) * 8] = ra[i];
      *(u16x8*)&lB[buf][(row * 8 + swz(row, slot0)) * 8] = rb[i];
    }
  };
  loadT(0);
  writeT(0);
  int cur = 0;
  for (int it = 0; it < 16; it++) {
    const int more = (it < 15);
    if (more) loadT((it + 1) * 64);
    __syncthreads();
    for (int kk = 0; kk < 2; kk++) {
      bf16x8 af[4], bfr[4];
      for (int fm = 0; fm < 4; fm++) af[fm] = frag8(lA[cur], wm * 64 + fm * 16 + (lane & 15), kk * 4 + g);
      for (int fn = 0; fn < 4; fn++) bfr[fn] = frag8(lB[cur], wn * 64 + fn * 16 + (lane & 15), kk * 4 + g);
      for (int fm = 0; fm < 4; fm++)
        for (int fn = 0; fn < 4; fn++)
          acc[fm][fn] = mfma32(af[fm], bfr[fn], acc[fm][fn]);
    }
    if (more) writeT(cur ^ 1);
    cur ^= 1;
  }
  if (proj != 2) {
    uint16_t* outp = (proj == 0 ? Q : K);
    for (int fm = 0; fm < 4; fm++)
      for (int fn = 0; fn < 4; fn++)
        for (int r = 0; r < 4; r++) {
          int row = m0 + wm * 64 + fm * 16 + g * 4 + r;
          int b = row >> 11, s = row & 2047;
          int col = n0 + wn * 64 + fn * 16 + (lane & 15);
          int h = (col >> 6) & 15, e = col & 63;
          outp[(((size_t)(b * 16 + h)) * 2048 + s) * 64 + e] = f2bf(acc[fm][fn][r]);
        }
  } else {
    __syncthreads();
    uint16_t* tv = (uint16_t*)lA;   // 32 KB: 128 cols x 256B
    for (int fm = 0; fm < 4; fm++)
      for (int fn = 0; fn < 4; fn++)
        for (int r = 0; r < 4; r++) {
          int rl = wm * 64 + fm * 16 + g * 4 + r;
          int cl = wn * 64 + fn * 16 + (lane & 15);
          int byte = rl * 2;
          *(uint16_t*)((char*)tv + cl * 256 + ((((byte >> 4)) ^ (cl & 15)) << 4) + (byte & 15)) =
              f2bf(acc[fm][fn][r]);
        }
    __syncthreads();
    const int b = m0 >> 11, s0 = m0 & 2047;
    const int c = tid >> 1, half = tid & 1;
    const int col = n0 + c;
    const int h = (col >> 6) & 15, e = col & 63;
    uint16_t* dst = Vt + (((size_t)(b * 16 + h)) * 64 + e) * 2048 + s0 + half * 64;
    for (int j = 0; j < 8; j++) {
      int rl = half * 64 + j * 8;
      u16x8 v = *(const u16x8*)((const char*)tv + c * 256 + (((rl >> 3) ^ (c & 15)) << 4));
      *(u16x8*)(dst + j * 8) = v;
    }
  }
}

// ---------------- causal flash attention: single-group, CHUNK=11, 3-way, no empties ----------------
__global__ __launch_bounds__(256) void attn1_k(const uint16_t* __restrict__ Q,
                                               const uint16_t* __restrict__ K,
                                               const uint16_t* __restrict__ Vt,
                                               uint16_t* __restrict__ Op0,
                                               uint16_t* __restrict__ Op1,
                                               uint16_t* __restrict__ Op2,
                                               float* __restrict__ lbuf) {
  __shared__ __attribute__((aligned(16))) uint16_t lK[2][64 * 64];
  __shared__ __attribute__((aligned(16))) uint16_t lV[2][64 * 64];
  __shared__ __attribute__((aligned(16))) uint16_t lP[4][16 * 64];
  const int tid = threadIdx.x, lane = tid & 63, wave = tid >> 6;
  const int g = lane >> 4, qrow = lane & 15;
  const int bx = blockIdx.x, h = blockIdx.y, b = blockIdx.z;
  const int qt = QT_TAB[bx], split = SP_TAB[bx];
  const int kt0 = split * 11;
  const int lim = qt + 1;
  const int kt1 = (kt0 + 11 < lim) ? kt0 + 11 : lim;
  const size_t bh = (size_t)(b * 16 + h);
  const uint16_t* Qg = Q + bh * 2048 * 64;
  const uint16_t* Kg = K + bh * 2048 * 64;
  const uint16_t* Vg = Vt + bh * 64 * 2048;
  uint16_t* lPw = lP[wave];
  bf16x8 ones;
  for (int j = 0; j < 8; j++) ones[j] = (__bf16)1.0f;
  const int lrow = lane >> 3, sl = lane & 7;
  auto STAGE = [&](int buf, int kt) {
    for (int i = 0; i < 2; i++) {
      int cb = (i * 4 + wave) * 64;
      int row = (cb >> 3) + lrow;
      int so = swz(row, sl) << 3;
      gload_lds16(Kg + (size_t)(kt * 64 + row) * 64 + so, &lK[buf][cb * 8]);
      gload_lds16(Vg + (size_t)row * 2048 + kt * 64 + so, &lV[buf][cb * 8]);
    }
  };
  const int q0 = qt * 64;
  bf16x8 qf[2];
  {
    int row = q0 + wave * 16 + qrow;
    for (int kk = 0; kk < 2; kk++)
      qf[kk] = asbf(*(const u16x8*)(Qg + (size_t)row * 64 + kk * 32 + g * 8));
  }
  f32x4 oacc[4] = {};
  f32x4 acc_l = {};
  STAGE(0, kt0);
  int buf = 0;
  for (int kt = kt0; kt < kt1; kt++) {
    __syncthreads();
    if (kt + 1 < kt1) STAGE(buf ^ 1, kt + 1);
    f32x4 s[4] = {};
    for (int kk = 0; kk < 2; kk++)
      for (int nf = 0; nf < 4; nf++)
        s[nf] = mfma32(frag8(lK[buf], nf * 16 + qrow, kk * 4 + g), qf[kk], s[nf]);
    if (kt == qt) {
      for (int nf = 0; nf < 4; nf++)
        for (int r = 0; r < 4; r++) {
          int kloc = nf * 16 + g * 4 + r;
          if (kloc > wave * 16 + qrow) s[nf][r] = -1e9f;
        }
    }
    for (int nf = 0; nf < 4; nf++) {
      float p0 = __builtin_amdgcn_exp2f(s[nf][0]);
      float p1 = __builtin_amdgcn_exp2f(s[nf][1]);
      float p2 = __builtin_amdgcn_exp2f(s[nf][2]);
      float p3 = __builtin_amdgcn_exp2f(s[nf][3]);
      u32x2 w;
      w[0] = ((uint32_t)f2bf_hw(p1) << 16) | f2bf_hw(p0);
      w[1] = ((uint32_t)f2bf_hw(p3) << 16) | f2bf_hw(p2);
      int slot = 2 * nf + (g >> 1);
      *(u32x2*)((char*)lPw + qrow * 128 + ((slot ^ (qrow & 7)) << 4) + ((g & 1) << 3)) = w;
    }
    for (int kk = 0; kk < 2; kk++) {
      bf16x8 pa = frag8(lPw, qrow, kk * 4 + g);
      acc_l = mfma32(pa, ones, acc_l);
      for (int df = 0; df < 4; df++)
        oacc[df] = mfma32(pa, frag8(lV[buf], df * 16 + qrow, kk * 4 + g), oacc[df]);
    }
    buf ^= 1;
  }
  uint16_t* Op = (split == 0) ? Op0 : (split == 1) ? Op1 : Op2;
  for (int df = 0; df < 4; df++)
    for (int r = 0; r < 4; r++) {
      int srow = q0 + wave * 16 + g * 4 + r;
      int e = df * 16 + qrow;
      Op[((size_t)b * 2048 + srow) * 1024 + h * 64 + e] = f2bf(oacc[df][r]);
    }
  if (qrow == 0) {
    for (int r = 0; r < 4; r++) {
      int srow = q0 + wave * 16 + g * 4 + r;
      lbuf[((size_t)(split * 2 + b) * 16 + h) * 2048 + srow] = acc_l[r];
    }
  }
}

// ---------------- merge (attn1): conditional 1/2/3-way by qt ----------------
__global__ __launch_bounds__(256) void merge3_k(const uint16_t* __restrict__ O0,
                                                const uint16_t* __restrict__ O1,
                                                const uint16_t* __restrict__ O2,
                                                const float* __restrict__ lbuf,
                                                uint16_t* __restrict__ out) {
  int i = (blockIdx.x * 256 + threadIdx.x) * 8;
  int sg = i >> 10;
  int b = sg >> 11, s = sg & 2047;
  int h = (i & 1023) >> 6;
  const int qt = s >> 6;
  const int nch = (qt + 11) / 11;               // ceil((qt+1)/11)
  float l = lbuf[((size_t)b * 16 + h) * 2048 + s];
  u16x8 o0 = *(const u16x8*)(O0 + i);
  float acc[8];
  for (int j = 0; j < 8; j++) acc[j] = bf2f(o0[j]);
  if (nch >= 2) {
    l += lbuf[((size_t)(2 + b) * 16 + h) * 2048 + s];
    u16x8 o1 = *(const u16x8*)(O1 + i);
    for (int j = 0; j < 8; j++) acc[j] += bf2f(o1[j]);
  }
  if (nch >= 3) {
    l += lbuf[((size_t)(4 + b) * 16 + h) * 2048 + s];
    u16x8 o2 = *(const u16x8*)(O2 + i);
    for (int j = 0; j < 8; j++) acc[j] += bf2f(o2[j]);
  }
  float inv = 1.f / l;
  u16x8 o;
  for (int j = 0; j < 8; j++) o[j] = f2bf(acc[j] * inv);
  *(u16x8*)(out + i) = o;
}

// ---------------- non-causal flash attention: dual-group (128 q/block), 4-way split ----------------
__global__ __launch_bounds__(256) void attn2_k(const uint16_t* __restrict__ Q,
                                               const uint16_t* __restrict__ K,
                                               const uint16_t* __restrict__ Vt,
                                               uint16_t* __restrict__ Op0,
                                               uint16_t* __restrict__ Op1,
                                               uint16_t* __restrict__ Op2,
                                               uint16_t* __restrict__ Op3,
                                               float* __restrict__ lbuf) {
  __shared__ __attribute__((aligned(16))) uint16_t lK[2][64 * 64];
  __shared__ __attribute__((aligned(16))) uint16_t lV[2][64 * 64];
  __shared__ __attribute__((aligned(16))) uint16_t lP[8][16 * 64];
  const int tid = threadIdx.x, lane = tid & 63, wave = tid >> 6;
  const int g = lane >> 4, qrow = lane & 15;
  const int bx = blockIdx.x, h = blockIdx.y, b = blockIdx.z;
  const int pair = bx >> 2, split = bx & 3;
  const int kt0 = split * 8, kt1 = kt0 + 8;
  const int q0 = pair * 128;
  const size_t bh = (size_t)(b * 16 + h);
  const uint16_t* Qg = Q + bh * 2048 * 64;
  const uint16_t* Kg = K + bh * 2048 * 64;
  const uint16_t* Vg = Vt + bh * 64 * 2048;
  uint16_t* lP0 = lP[wave * 2];
  uint16_t* lP1 = lP[wave * 2 + 1];
  bf16x8 ones;
  for (int j = 0; j < 8; j++) ones[j] = (__bf16)1.0f;
  const int lrow = lane >> 3, sl = lane & 7;
  auto STAGE = [&](int buf, int kt) {
    for (int i = 0; i < 2; i++) {
      int cb = (i * 4 + wave) * 64;
      int row = (cb >> 3) + lrow;
      int so = swz(row, sl) << 3;
      gload_lds16(Kg + (size_t)(kt * 64 + row) * 64 + so, &lK[buf][cb * 8]);
      gload_lds16(Vg + (size_t)row * 2048 + kt * 64 + so, &lV[buf][cb * 8]);
    }
  };
  bf16x8 qf[2][2];
#pragma unroll
  for (int grp = 0; grp < 2; grp++) {
    int row = q0 + grp * 64 + wave * 16 + qrow;
    for (int kk = 0; kk < 2; kk++)
      qf[grp][kk] = asbf(*(const u16x8*)(Qg + (size_t)row * 64 + kk * 32 + g * 8));
  }
  f32x4 oacc[2][4] = {};
  f32x4 acc_l[2] = {};
  auto storeP = [&](uint16_t* lPw, f32x4 (&s)[4]) {
#pragma unroll
    for (int nf = 0; nf < 4; nf++) {
      float p0 = __builtin_amdgcn_exp2f(s[nf][0]);
      float p1 = __builtin_amdgcn_exp2f(s[nf][1]);
      float p2 = __builtin_amdgcn_exp2f(s[nf][2]);
      float p3 = __builtin_amdgcn_exp2f(s[nf][3]);
      u32x2 w;
      w[0] = ((uint32_t)f2bf_hw(p1) << 16) | f2bf_hw(p0);
      w[1] = ((uint32_t)f2bf_hw(p3) << 16) | f2bf_hw(p2);
      int slot = 2 * nf + (g >> 1);
      *(u32x2*)((char*)lPw + qrow * 128 + ((slot ^ (qrow & 7)) << 4) + ((g & 1) << 3)) = w;
    }
  };
  STAGE(0, kt0);
  int buf = 0;
  for (int kt = kt0; kt < kt1; kt++) {
    __syncthreads();
    if (kt + 1 < kt1) STAGE(buf ^ 1, kt + 1);
    f32x4 s0[4] = {}, s1[4] = {};
#pragma unroll
    for (int kk = 0; kk < 2; kk++)
#pragma unroll
      for (int nf = 0; nf < 4; nf++) {
        bf16x8 kf = frag8(lK[buf], nf * 16 + qrow, kk * 4 + g);
        s0[nf] = mfma32(kf, qf[0][kk], s0[nf]);
        s1[nf] = mfma32(kf, qf[1][kk], s1[nf]);
      }
    storeP(lP0, s0);
    storeP(lP1, s1);
#pragma unroll
    for (int kk = 0; kk < 2; kk++) {
      bf16x8 pa0 = frag8(lP0, qrow, kk * 4 + g);
      bf16x8 pa1 = frag8(lP1, qrow, kk * 4 + g);
      acc_l[0] = mfma32(pa0, ones, acc_l[0]);
      acc_l[1] = mfma32(pa1, ones, acc_l[1]);
#pragma unroll
      for (int df = 0; df < 4; df++) {
        bf16x8 vf = frag8(lV[buf], df * 16 + qrow, kk * 4 + g);
        oacc[0][df] = mfma32(pa0, vf, oacc[0][df]);
        oacc[1][df] = mfma32(pa1, vf, oacc[1][df]);
      }
    }
    buf ^= 1;
  }
  uint16_t* Op = (split == 0) ? Op0 : (split == 1) ? Op1 : (split == 2) ? Op2 : Op3;
#pragma unroll
  for (int grp = 0; grp < 2; grp++)
    for (int df = 0; df < 4; df++)
      for (int r = 0; r < 4; r++) {
        int srow = q0 + grp * 64 + wave * 16 + g * 4 + r;
        int e = df * 16 + qrow;
        Op[((size_t)b * 2048 + srow) * 1024 + h * 64 + e] = f2bf(oacc[grp][df][r]);
      }
  if (qrow == 0) {
#pragma unroll
    for (int grp = 0; grp < 2; grp++)
      for (int r = 0; r < 4; r++) {
        int srow = q0 + grp * 64 + wave * 16 + g * 4 + r;
        lbuf[((size_t)(split * 2 + b) * 16 + h) * 2048 + srow] = acc_l[grp][r];
      }
  }
}

// ---------------- merge (attn2): 4-way ----------------
__global__ __launch_bounds__(256) void merge4_k(const uint16_t* __restrict__ O0,
                                                const uint16_t* __restrict__ O1,
                                                const uint16_t* __restrict__ O2,
                                                const uint16_t* __restrict__ O3,
                                                const float* __restrict__ lbuf,
                                                uint16_t* __restrict__ out) {
  int i = (blockIdx.x * 256 + threadIdx.x) * 8;
  int sg = i >> 10;
  int b = sg >> 11, s = sg & 2047;
  int h = (i & 1023) >> 6;
  float l = 0.f;
  for (int sp = 0; sp < 4; sp++)
    l += lbuf[((size_t)(sp * 2 + b) * 16 + h) * 2048 + s];
  float inv = 1.f / l;
  u16x8 o0 = *(const u16x8*)(O0 + i);
  u16x8 o1 = *(const u16x8*)(O1 + i);
  u16x8 o2 = *(const u16x8*)(O2 + i);
  u16x8 o3 = *(const u16x8*)(O3 + i);
  u16x8 o;
  for (int j = 0; j < 8; j++)
    o[j] = f2bf((bf2f(o0[j]) + bf2f(o1[j]) + bf2f(o2[j]) + bf2f(o3[j])) * inv);
  *(u16x8*)(out + i) = o;
}

// ---------------- FFN GEMM 1: C[M,N] = A[M,K] @ Bt[N,K]^T (+bias raw, relu), R8 dbuf ----------------
__global__ __launch_bounds__(256) void ff_k(const uint16_t* __restrict__ A,
                                            const uint16_t* __restrict__ Bt,
                                            const void* __restrict__ bias,
                                            uint16_t* __restrict__ C, int Kdim, int N,
                                            const uint32_t* __restrict__ flag) {
  __shared__ __attribute__((aligned(16))) uint16_t lA[2][128 * 64];
  __shared__ __attribute__((aligned(16))) uint16_t lB[2][128 * 64];
  const int isbf = (int)flag[0];
  const int tid = threadIdx.x, lane = tid & 63, wave = tid >> 6;
  const int g = lane >> 4;
  const int m0 = blockIdx.x * 128, n0 = blockIdx.y * 128;
  const int wm = wave >> 1, wn = wave & 1;
  f32x4 acc[4][4] = {};
  u16x8 ra[4], rb[4];
  const int row0 = tid >> 3, slot0 = tid & 7;
  auto loadT = [&](int kt) {
    for (int i = 0; i < 4; i++) {
      int row = row0 + i * 32;
      ra[i] = *(const u16x8*)(A + (size_t)(m0 + row) * Kdim + kt + slot0 * 8);
      rb[i] = *(const u16x8*)(Bt + (size_t)(n0 + row) * Kdim + kt + slot0 * 8);
    }
  };
  auto writeT = [&](int buf) {
    for (int i = 0; i < 4; i++) {
      int row = row0 + i * 32;
      *(u16x8*)&lA[buf][(row * 8 + swz(row, slot0)) * 8] = ra[i];
      *(u16x8*)&lB[buf][(row * 8 + swz(row, slot0)) * 8] = rb[i];
    }
  };
  loadT(0);
  writeT(0);
  int cur = 0;
  const int nit = Kdim >> 6;
  for (int it = 0; it < nit; it++) {
    const int more = (it < nit - 1);
    if (more) loadT((it + 1) * 64);
    __syncthreads();
    for (int kk = 0; kk < 2; kk++) {
      bf16x8 af[4], bfr[4];
      for (int fm = 0; fm < 4; fm++) af[fm] = frag8(lA[cur], wm * 64 + fm * 16 + (lane & 15), kk * 4 + g);
      for (int fn = 0; fn < 4; fn++) bfr[fn] = frag8(lB[cur], wn * 64 + fn * 16 + (lane & 15), kk * 4 + g);
      for (int fm = 0; fm < 4; fm++)
        for (int fn = 0; fn < 4; fn++)
          acc[fm][fn] = mfma32(af[fm], bfr[fn], acc[fm][fn]);
    }
    if (more) writeT(cur ^ 1);
    cur ^= 1;
  }
  for (int fm = 0; fm < 4; fm++)
    for (int fn = 0; fn < 4; fn++) {
      int col = n0 + wn * 64 + fn * 16 + (lane & 15);
      float bv = isbf ? bf2f(((const uint16_t*)bias)[col]) : ((const float*)bias)[col];
      for (int r = 0; r < 4; r++) {
        int row = m0 + wm * 64 + fm * 16 + g * 4 + r;
        float v = acc[fm][fn][r] + bv;
        v = fmaxf(v, 0.f);
        C[(size_t)row * N + col] = f2bf(v);
      }
    }
}

// ---------------- FFN GEMM 2: BM=64 x BN=128 tile, writes d_out (flag dtype) ----------------
// grid (M/64, N/128) = (64, 8) = 512 blocks. Waves: wm=wave>>1 (2) x wn=wave&1 (2),
// each wave 32 rows x 64 cols -> acc[2][4]. LDS 48KB.
__global__ __launch_bounds__(256) void ff64_k(const uint16_t* __restrict__ A,
                                              const uint16_t* __restrict__ Bt,
                                              const void* __restrict__ bias,
                                              void* __restrict__ C, int Kdim, int N,
                                              const uint32_t* __restrict__ flag) {
  __shared__ __attribute__((aligned(16))) uint16_t lA[2][64 * 64];
  __shared__ __attribute__((aligned(16))) uint16_t lB[2][128 * 64];
  const int isbf = (int)flag[0];
  const int tid = threadIdx.x, lane = tid & 63, wave = tid >> 6;
  const int g = lane >> 4;
  const int m0 = blockIdx.x * 64, n0 = blockIdx.y * 128;
  const int wm = wave >> 1, wn = wave & 1;
  f32x4 acc[2][4] = {};
  u16x8 ra[2], rb[4];
  const int row0 = tid >> 3, slot0 = tid & 7;
  auto loadT = [&](int kt) {
    for (int i = 0; i < 2; i++) {
      int row = row0 + i * 32;
      ra[i] = *(const u16x8*)(A + (size_t)(m0 + row) * Kdim + kt + slot0 * 8);
    }
    for (int i = 0; i < 4; i++) {
      int row = row0 + i * 32;
      rb[i] = *(const u16x8*)(Bt + (size_t)(n0 + row) * Kdim + kt + slot0 * 8);
    }
  };
  auto writeT = [&](int buf) {
    for (int i = 0; i < 2; i++) {
      int row = row0 + i * 32;
      *(u16x8*)&lA[buf][(row * 8 + swz(row, slot0)) * 8] = ra[i];
    }
    for (int i = 0; i < 4; i++) {
      int row = row0 + i * 32;
      *(u16x8*)&lB[buf][(row * 8 + swz(row, slot0)) * 8] = rb[i];
    }
  };
  loadT(0);
  writeT(0);
  int cur = 0;
  const int nit = Kdim >> 6;
  for (int it = 0; it < nit; it++) {
    const int more = (it < nit - 1);
    if (more) loadT((it + 1) * 64);
    __syncthreads();
    for (int kk = 0; kk < 2; kk++) {
      bf16x8 af[2], bfr[4];
      for (int fm = 0; fm < 2; fm++) af[fm] = frag8(lA[cur], wm * 32 + fm * 16 + (lane & 15), kk * 4 + g);
      for (int fn = 0; fn < 4; fn++) bfr[fn] = frag8(lB[cur], wn * 64 + fn * 16 + (lane & 15), kk * 4 + g);
      for (int fm = 0; fm < 2; fm++)
        for (int fn = 0; fn < 4; fn++)
          acc[fm][fn] = mfma32(af[fm], bfr[fn], acc[fm][fn]);
    }
    if (more) writeT(cur ^ 1);
    cur ^= 1;
  }
  for (int fm = 0; fm < 2; fm++)
    for (int fn = 0; fn < 4; fn++) {
      int col = n0 + wn * 64 + fn * 16 + (lane & 15);
      float bv = isbf ? bf2f(((const uint16_t*)bias)[col]) : ((const float*)bias)[col];
      for (int r = 0; r < 4; r++) {
        int row = m0 + wm * 32 + fm * 16 + g * 4 + r;
        float v = acc[fm][fn][r] + bv;
        size_t idx = (size_t)row * N + col;
        if (isbf) ((uint16_t*)C)[idx] = f2bf(v);
        else      ((float*)C)[idx] = v;
      }
    }
}

extern "C" void kernel_launch(void* const* d_in, const int* in_sizes, int n_in,
                              void* d_out, int out_size, void* d_ws, size_t ws_size,
                              hipStream_t stream) {
  const void* de_x = d_in[0];
  const void* en_x = d_in[1];
  const void* mask = d_in[2];
  const void* Wq = d_in[3];
  const void* Wk = d_in[4];
  const void* Wv = d_in[5];
  const void* W1 = d_in[6];
  const void* b1 = d_in[7];
  const void* W2 = d_in[8];
  const void* b2 = d_in[9];

  uint16_t* ws = (uint16_t*)d_ws;
  const size_t M1 = (size_t)1 << 20;
  uint32_t* flag = (uint32_t*)ws;
  float* lbuf = (float*)(ws + 8192);           // [8][b-folded][16][2048] f32 = 1MB
  uint16_t* Wtq = ws + 1 * M1;                 // [3][16][64][1024] contiguous (Q scaled)
  uint16_t* W1t = ws + 4 * M1;                 // [2048][1024]
  uint16_t* W2t = ws + 6 * M1;                 // [1024][2048]
  uint16_t* de_c = ws + 8 * M1;                // f32 path only
  uint16_t* en_c = ws + 12 * M1;
  uint16_t* Qb  = ws + 16 * M1;                // [B,H,S,64]
  uint16_t* Kb  = ws + 20 * M1;
  uint16_t* Vtb = ws + 24 * M1;                // [B,H,64,S]
  uint16_t* h1  = ws + 28 * M1;
  uint16_t* h2  = ws + 32 * M1;
  uint16_t* ff1 = Qb;                          // reuse
  // attn1 partials: de_c (dead after proj1), h2 (free until ff1), h1 (merge in-place)
  // attn2 partials: de_c, en_c (dead after proj2), h1 (dead after proj2), h2 (merge in-place)

  const int NX = 2 * 2048 * 1024;
  dim3 blk(256);

  probe_k<<<1, 1, 0, stream>>>((const uint32_t*)mask, flag);
  cvt_both_k<<<2048, blk, 0, stream>>>(de_x, de_c, en_x, en_c, NX, flag); // no-op when bf16
  transpose_all_k<<<7168, blk, 0, stream>>>(Wq, Wk, Wv, W1, W2, Wtq, W1t, W2t, flag);
  // MHA1: q=k=v=de_x, causal, balanced CHUNK=11 3-way split-K
  proj_k<<<dim3(32, 24), blk, 0, stream>>>(de_c, de_x, de_c, de_x, Wtq, Qb, Kb, Vtb, flag);
  attn1_k<<<dim3(63, 16, 2), blk, 0, stream>>>(Qb, Kb, Vtb, de_c, h2, h1, lbuf);
  merge3_k<<<2048, blk, 0, stream>>>(de_c, h2, h1, lbuf, h1);
  // MHA2: q=k=en_x, v=h1, no mask, dual-group 4-way split-K
  proj_k<<<dim3(32, 24), blk, 0, stream>>>(en_c, en_x, h1, h1, Wtq, Qb, Kb, Vtb, flag);
  attn2_k<<<dim3(64, 16, 2), blk, 0, stream>>>(Qb, Kb, Vtb, de_c, en_c, h1, h2, lbuf);
  merge4_k<<<2048, blk, 0, stream>>>(de_c, en_c, h1, h2, lbuf, h2);
  // FFN: ff1 128x128 (relu), ff2 64x128 tile writing d_out directly
  ff_k<<<dim3(32, 16), blk, 0, stream>>>(h2, W1t, b1, ff1, 1024, 2048, flag);
  ff64_k<<<dim3(64, 8), blk, 0, stream>>>(ff1, W2t, b2, d_out, 2048, 1024, flag);
}